// Round 11
// baseline (573.954 us; speedup 1.0000x reference)
//
#include <hip/hip_runtime.h>
#include <math.h>

#define INV_SQRT1P 0.99999500003749968754f   // 1/sqrt(1+1e-5)

typedef short v8s  __attribute__((ext_vector_type(8)));
typedef float v16f __attribute__((ext_vector_type(16)));

static __device__ __forceinline__ float lrelu(float f){ return f >= 0.0f ? f : 0.2f*f; }

static __device__ __forceinline__ int lanecnt_below(unsigned long long m){
  int c = __builtin_amdgcn_mbcnt_lo((unsigned)m, 0u);
  return __builtin_amdgcn_mbcnt_hi((unsigned)(m >> 32), c);
}

// ---------------- extract xyz (C=3) for BOTH inputs in one launch ----------------
__global__ void k_ext3(const float* __restrict__ f1, const float* __restrict__ f2,
                       float* __restrict__ out){
  int i = blockIdx.x*256 + threadIdx.x;
  int half = 8*3*1024;
  if (i >= 2*half) return;
  const float* f = (i < half) ? f1 : f2;
  int boff = (i < half) ? 0 : 8;
  int ii = (i < half) ? i : i - half;
  int n  = ii & 1023;
  int bc = ii >> 10;
  int c  = bc % 3;
  int b  = bc / 3;
  out[((size_t)(((b+boff)<<10)+n))*3 + c] = f[((size_t)(b*131 + c) << 10) + n];
}

// ---------------- extract sem (C=128) via LDS tile transpose, both inputs ----------
__global__ __launch_bounds__(256) void k_extT(const float* __restrict__ f1,
    const float* __restrict__ f2, float* __restrict__ out){
  __shared__ float T[32][65];
  int bid = blockIdx.x;              // 16 ntile x 4 ctile x 16 (input*8+b)
  int nt = bid & 15;
  int ct = (bid >> 4) & 3;
  int bb = bid >> 6;                 // 0..15
  const float* f = (bb < 8) ? f1 : f2;
  int b = bb & 7;
  int tid = threadIdx.x;
  #pragma unroll
  for (int it=0; it<8; it++){
    int cc = it*4 + (tid >> 6);      // 0..31
    int nn = tid & 63;
    T[cc][nn] = f[((size_t)(b*131 + 3 + ct*32 + cc) << 10) + nt*64 + nn];
  }
  __syncthreads();
  size_t rowb = ((size_t)bb << 10) + nt*64;
  #pragma unroll
  for (int it=0; it<8; it++){
    int nn = it*8 + (tid >> 5);      // 0..63
    int c  = tid & 31;
    out[(rowb + nn)*128 + ct*32 + c] = T[c][nn];
  }
}

// ---------------- pack body (wpack blocks first, then X-pack blocks) ----------------
static __device__ __forceinline__ void pw_body(int bid, int tid,
    const float* __restrict__ X, unsigned short* __restrict__ PH,
    unsigned short* __restrict__ PL, float* __restrict__ xxout,
    const float* __restrict__ Wm, unsigned short* __restrict__ PWH,
    unsigned short* __restrict__ PWL,
    int C, int Kp, int O, int nwblk, int nrowsB, int wsplit, int doxx){
  int nkc = Kp >> 4;
  if (bid < nwblk){
    int gid = bid*256 + tid;
    int nchunk = (nrowsB/32)*nkc;
    if (gid >= nchunk*64) return;
    int lane = gid & 63;
    int chunk = gid >> 6;
    int jb = chunk / nkc, kc = chunk - jb*nkc;
    int j = jb*32 + (lane & 31);
    int k0 = kc*16 + ((lane>>5)<<3);
    unsigned short h[8], lo[8];
    #pragma unroll
    for (int t=0;t<8;t++){
      int k = k0 + t;
      float x = 0.f;
      if (k < C){
        if (wsplit) x = (j < O) ? Wm[(size_t)j*2*C + k] : Wm[(size_t)(j-O)*2*C + C + k];
        else        x = Wm[(size_t)j*C + k];
      }
      unsigned u = __float_as_uint(x);
      unsigned h16 = (u + 0x7fffu + ((u>>16)&1u)) >> 16;
      float hf = __uint_as_float(h16 << 16);
      float lf = x - hf;
      unsigned ul = __float_as_uint(lf);
      unsigned l16 = (ul + 0x7fffu + ((ul>>16)&1u)) >> 16;
      h[t] = (unsigned short)h16; lo[t] = (unsigned short)l16;
    }
    size_t o = (size_t)chunk*512 + lane*8;
    *(v8s*)(PWH + o) = *(v8s*)h;
    *(v8s*)(PWL + o) = *(v8s*)lo;
  } else {
    int gid = (bid - nwblk)*256 + tid;      // grid exact: 512*nkc*64 threads
    int lane = gid & 63;
    int chunk = gid >> 6;
    int rb = chunk / nkc, kc = chunk - rb*nkc;
    int row = rb*32 + (lane & 31);
    int k0 = kc*16 + ((lane>>5)<<3);
    unsigned short h[8], lo[8];
    const float* Xr = X + (size_t)row*C;
    #pragma unroll
    for (int j=0;j<8;j++){
      int k = k0 + j;
      float x = (k < C) ? Xr[k] : 0.f;
      unsigned u = __float_as_uint(x);
      unsigned h16 = (u + 0x7fffu + ((u>>16)&1u)) >> 16;
      float hf = __uint_as_float(h16 << 16);
      float lf = x - hf;
      unsigned ul = __float_as_uint(lf);
      unsigned l16 = (ul + 0x7fffu + ((ul>>16)&1u)) >> 16;
      h[j] = (unsigned short)h16; lo[j] = (unsigned short)l16;
    }
    size_t o = (size_t)chunk*512 + lane*8;
    *(v8s*)(PH + o) = *(v8s*)h;
    *(v8s*)(PL + o) = *(v8s*)lo;
    if (doxx && kc == 0 && (lane & 32) == 0){
      float s = 0.f;
      for (int c=0;c<C;c++) s += Xr[c]*Xr[c];    // ascending order == old k_xx
      xxout[row] = s;
    }
  }
}

// merged pack for two independent paths
__global__ __launch_bounds__(256) void k_pw2(
    const float* __restrict__ XA, unsigned short* __restrict__ PHa,
    unsigned short* __restrict__ PLa, float* __restrict__ xxA,
    const float* __restrict__ WA, unsigned short* __restrict__ PWHa,
    unsigned short* __restrict__ PWLa, int CA, int KpA, int OA, int nwblkA, int nblkA,
    const float* __restrict__ XB, unsigned short* __restrict__ PHb,
    unsigned short* __restrict__ PLb, float* __restrict__ xxB,
    const float* __restrict__ WB, unsigned short* __restrict__ PWHb,
    unsigned short* __restrict__ PWLb, int CB, int KpB, int OB, int nwblkB){
  int bid = blockIdx.x;
  if (bid < nblkA)
    pw_body(bid, threadIdx.x, XA, PHa, PLa, xxA, WA, PWHa, PWLa, CA, KpA, OA, nwblkA, 2*OA, 1, 1);
  else
    pw_body(bid - nblkA, threadIdx.x, XB, PHb, PLb, xxB, WB, PWHb, PWLb, CB, KpB, OB, nwblkB, 2*OB, 1, 1);
}

// single pack (emb combine)
__global__ __launch_bounds__(256) void k_pw(const float* __restrict__ X,
    unsigned short* __restrict__ PH, unsigned short* __restrict__ PL,
    float* __restrict__ xxout, const float* __restrict__ Wm,
    unsigned short* __restrict__ PWH, unsigned short* __restrict__ PWL,
    int C, int Kp, int O, int nwblk, int nrowsB, int wsplit, int doxx){
  pw_body(blockIdx.x, threadIdx.x, X, PH, PL, xxout, Wm, PWH, PWL,
          C, Kp, O, nwblk, nrowsB, wsplit, doxx);
}

// ---------------- ymf body: Y = X.Wp^T tile per wave ----------------
static __device__ __forceinline__ void ymf_body(int gw, int l,
    const unsigned short* __restrict__ PH, const unsigned short* __restrict__ PL,
    const unsigned short* __restrict__ PWH, const unsigned short* __restrict__ PWL,
    float* __restrict__ Y, int nkc, int N, int npair){
  int mt = gw / npair;
  int pair = gw - mt*npair;
  int jb0 = pair*2, jb1 = pair*2 + 1;
  size_t ao  = ((size_t)mt*nkc)*512 + l*8;
  size_t b0o = ((size_t)jb0*nkc)*512 + l*8;
  size_t b1o = ((size_t)jb1*nkc)*512 + l*8;
  v16f acc0, acc1;
  #pragma unroll
  for (int i=0;i<16;i++){ acc0[i] = 0.f; acc1[i] = 0.f; }
  for (int kc=0; kc<nkc; kc++){
    v8s Ah  = *(const v8s*)(PH + ao);
    v8s Al  = *(const v8s*)(PL + ao);
    v8s B0h = *(const v8s*)(PWH + b0o);
    v8s B0l = *(const v8s*)(PWL + b0o);
    v8s B1h = *(const v8s*)(PWH + b1o);
    v8s B1l = *(const v8s*)(PWL + b1o);
    acc0 = __builtin_amdgcn_mfma_f32_32x32x16_bf16(Ah, B0h, acc0, 0, 0, 0);
    acc1 = __builtin_amdgcn_mfma_f32_32x32x16_bf16(Ah, B1h, acc1, 0, 0, 0);
    acc0 = __builtin_amdgcn_mfma_f32_32x32x16_bf16(Ah, B0l, acc0, 0, 0, 0);
    acc1 = __builtin_amdgcn_mfma_f32_32x32x16_bf16(Ah, B1l, acc1, 0, 0, 0);
    acc0 = __builtin_amdgcn_mfma_f32_32x32x16_bf16(Al, B0h, acc0, 0, 0, 0);
    acc1 = __builtin_amdgcn_mfma_f32_32x32x16_bf16(Al, B1h, acc1, 0, 0, 0);
    ao += 512; b0o += 512; b1o += 512;
  }
  int rbase = mt*32;
  int c0 = pair*64 + (l & 31), c1 = c0 + 32;
  #pragma unroll
  for (int r=0;r<16;r++){
    int rl_ = (r&3) + ((r>>2)<<3) + ((l>>5)<<2);
    float* dst = Y + (size_t)(rbase + rl_)*N;
    dst[c0] = acc0[r];
    dst[c1] = acc1[r];
  }
}

// ---------------- dtk body: distances + exact top-20 for rowblock rb ----------------
static __device__ void dtk_body(float (&Sl)[16][1024], int t, int wave, int l,
    const unsigned short* __restrict__ PH, const unsigned short* __restrict__ PL,
    const float* __restrict__ xx, int* __restrict__ idx, int nkc){
  int rb = ((t & 7) << 6) | (t >> 3);   // XCD swizzle over 512 dtk blocks
  int batch = rb >> 5;
  const float* xxb = xx + (batch<<10);
  int rbase_local = (rb & 31)*32;

  v16f acc[4];
  #pragma unroll
  for (int i=0;i<4;i++){
    #pragma unroll
    for (int j=0;j<16;j++) acc[i][j] = 0.f;
  }
  #pragma unroll
  for (int pp=0; pp<2; pp++){
    int pair = wave*2 + pp;
    size_t a   = ((size_t)rb*nkc)*512 + l*8;
    size_t b0o = ((size_t)(batch*32 + 2*pair)*nkc)*512 + l*8;
    size_t b1o = b0o + (size_t)nkc*512;
    for (int kc=0; kc<nkc; kc++){
      v8s Ah  = *(const v8s*)(PH + a);
      v8s Al  = *(const v8s*)(PL + a);
      v8s B0h = *(const v8s*)(PH + b0o);
      v8s B0l = *(const v8s*)(PL + b0o);
      v8s B1h = *(const v8s*)(PH + b1o);
      v8s B1l = *(const v8s*)(PL + b1o);
      acc[2*pp]   = __builtin_amdgcn_mfma_f32_32x32x16_bf16(Ah, B0h, acc[2*pp],   0, 0, 0);
      acc[2*pp+1] = __builtin_amdgcn_mfma_f32_32x32x16_bf16(Ah, B1h, acc[2*pp+1], 0, 0, 0);
      acc[2*pp]   = __builtin_amdgcn_mfma_f32_32x32x16_bf16(Ah, B0l, acc[2*pp],   0, 0, 0);
      acc[2*pp+1] = __builtin_amdgcn_mfma_f32_32x32x16_bf16(Ah, B1l, acc[2*pp+1], 0, 0, 0);
      acc[2*pp]   = __builtin_amdgcn_mfma_f32_32x32x16_bf16(Al, B0h, acc[2*pp],   0, 0, 0);
      acc[2*pp+1] = __builtin_amdgcn_mfma_f32_32x32x16_bf16(Al, B1h, acc[2*pp+1], 0, 0, 0);
      a += 512; b0o += 512; b1o += 512;
    }
  }

  #pragma unroll
  for (int h=0; h<2; h++){
    #pragma unroll
    for (int pp=0; pp<2; pp++){
      int pair = wave*2 + pp;
      int c0 = pair*64 + (l & 31), c1 = c0 + 32;
      float xc0 = xxb[c0], xc1 = xxb[c1];
      #pragma unroll
      for (int r = 0; r < 8; r++){
        int rr = h*8 + r;
        int rl = (rr&3) + (((rr>>2)&1)<<3) + ((l>>5)<<2);  // 0..15
        float xr = xxb[rbase_local + h*16 + rl];
        Sl[rl][c0] = 2.f*acc[2*pp][rr]   - xr - xc0;
        Sl[rl][c1] = 2.f*acc[2*pp+1][rr] - xr - xc1;
      }
    }
    __syncthreads();
    {
      int hi = l >> 5;
      int li = l & 31;
      int rloc = wave*2 + hi;
      int grow = rb*32 + h*16 + rloc;
      int out_base = grow*20;
      unsigned long long hm = hi ? 0xFFFFFFFF00000000ull : 0x00000000FFFFFFFFull;

      unsigned kv[32];
      #pragma unroll
      for (int j=0;j<32;j++){
        unsigned u = __float_as_uint(Sl[rloc][li + 32*j]);
        kv[j] = (u & 0x80000000u) ? ~u : (u | 0x80000000u);
      }

      unsigned lmax = kv[0];
      #pragma unroll
      for (int j=1;j<32;j++) lmax = lmax > kv[j] ? lmax : kv[j];

      unsigned tau = 0u;
      #pragma unroll
      for (int bit=31; bit>=0; --bit){
        unsigned cand = tau | (1u << bit);
        unsigned long long M = __ballot(lmax >= cand);
        int c = hi ? __popc((unsigned)(M >> 32)) : __popc((unsigned)M);
        tau = (c >= 20) ? cand : tau;
      }

      unsigned long long* sl = (unsigned long long*)&Sl[rloc][0];
      sl[li] = 0ull; sl[li+32] = 0ull;
      int b2 = 0;
      #pragma unroll
      for (int j=0;j<32;j++){
        bool p = kv[j] >= tau;
        unsigned long long M = __ballot(p) & hm;
        if (p){
          int s = b2 + lanecnt_below(M);
          if (s < 64) sl[s] = ((unsigned long long)kv[j] << 32) | (unsigned)(li + 32*j);
        }
        b2 += __popcll(M);
      }

      if (b2 <= 64){
        unsigned long long pk0 = sl[li], pk1 = sl[li+32];
        unsigned vcur = 0u;
        #pragma unroll
        for (int bit=31; bit>=0; --bit){
          unsigned long long cc = (unsigned long long)(vcur | (1u << bit)) << 32;
          unsigned long long B0 = __ballot(pk0 >= cc);
          unsigned long long B1 = __ballot(pk1 >= cc);
          int clo = __popc((unsigned)B0) + __popc((unsigned)B1);
          int chi = __popc((unsigned)(B0>>32)) + __popc((unsigned)(B1>>32));
          int c = hi ? chi : clo;
          vcur = (c >= 20) ? (vcur | (1u << bit)) : vcur;
        }
        unsigned k0 = (unsigned)(pk0 >> 32), k1 = (unsigned)(pk1 >> 32);
        unsigned long long G0 = __ballot(k0 > vcur) & hm;
        unsigned long long G1 = __ballot(k1 > vcur) & hm;
        int ng0 = __popcll(G0);
        int c1  = ng0 + __popcll(G1);
        if (k0 > vcur) idx[out_base + lanecnt_below(G0)] = (int)(pk0 & 0xffffffffu);
        if (k1 > vcur) idx[out_base + ng0 + lanecnt_below(G1)] = (int)(pk1 & 0xffffffffu);
        unsigned long long E0 = __ballot(k0 == vcur) & hm;
        unsigned long long E1 = __ballot(k1 == vcur) & hm;
        int ne0 = __popcll(E0);
        if (k0 == vcur){ int s = c1 + lanecnt_below(E0); if (s < 20) idx[out_base + s] = (int)(pk0 & 0xffffffffu); }
        if (k1 == vcur){ int s = c1 + ne0 + lanecnt_below(E1); if (s < 20) idx[out_base + s] = (int)(pk1 & 0xffffffffu); }
      } else {
        unsigned cur = 0u;
        #pragma unroll 1
        for (int bit=31; bit>=0; --bit){
          unsigned cand = cur | (1u << bit);
          int lc = 0;
          #pragma unroll
          for (int j=0;j<32;j++) lc += (kv[j] >= cand) ? 1 : 0;
          #pragma unroll
          for (int off=1; off<32; off<<=1) lc += __shfl_xor(lc, off, 64);
          cur = (lc >= 20) ? cand : cur;
        }
        int bse = 0;
        #pragma unroll 1
        for (int j=0;j<32;j++){
          unsigned long long Mg = __ballot(kv[j] > cur) & hm;
          if (kv[j] > cur){ int s = bse + lanecnt_below(Mg); idx[out_base + s] = li + 32*j; }
          bse += __popcll(Mg);
        }
        #pragma unroll 1
        for (int j=0;j<32;j++){
          unsigned long long Me = __ballot(kv[j] == cur) & hm;
          if (kv[j] == cur){ int s = bse + lanecnt_below(Me); if (s < 20) idx[out_base + s] = li + 32*j; }
          bse += __popcll(Me);
          if (bse >= 20) break;
        }
      }
    }
    __syncthreads();
  }
}

// merged Y-GEMM + distance/top-20 for TWO independent paths
__global__ __launch_bounds__(512) void k_dy2(
    const unsigned short* __restrict__ PHa, const unsigned short* __restrict__ PLa,
    const unsigned short* __restrict__ PWHa, const unsigned short* __restrict__ PWLa,
    const float* __restrict__ xxA, int* __restrict__ idxA, float* __restrict__ Ya,
    int KpA, int NA, int npairA, int nymfA,
    const unsigned short* __restrict__ PHb, const unsigned short* __restrict__ PLb,
    const unsigned short* __restrict__ PWHb, const unsigned short* __restrict__ PWLb,
    const float* __restrict__ xxB, int* __restrict__ idxB, float* __restrict__ Yb,
    int KpB, int NB, int npairB, int nymfB){
  __shared__ float Sl[16][1024];          // 64 KB
  int wave = threadIdx.x >> 6;
  int l = threadIdx.x & 63;
  int bid = (int)blockIdx.x;
  int nblkA = nymfA + 512;
  if (bid < nblkA){
    if (bid < nymfA)
      ymf_body(bid*8 + wave, l, PHa, PLa, PWHa, PWLa, Ya, KpA >> 4, NA, npairA);
    else
      dtk_body(Sl, bid - nymfA, wave, l, PHa, PLa, xxA, idxA, KpA >> 4);
  } else {
    int b2 = bid - nblkA;
    if (b2 < nymfB)
      ymf_body(b2*8 + wave, l, PHb, PLb, PWHb, PWLb, Yb, KpB >> 4, NB, npairB);
    else
      dtk_body(Sl, b2 - nymfB, wave, l, PHb, PLb, xxB, idxB, KpB >> 4);
  }
}

// ---------------- EMB combine via MFMA: EMB = lrelu(eg*(X3S3.ew^T)*inv + eb) --------
__global__ __launch_bounds__(256) void k_emb(const unsigned short* __restrict__ PH,
    const unsigned short* __restrict__ PL, const unsigned short* __restrict__ PWH,
    const unsigned short* __restrict__ PWL, const float* __restrict__ eg,
    const float* __restrict__ eb, float* __restrict__ EMB){
  int w = threadIdx.x >> 6;
  int l = threadIdx.x & 63;
  int gw = blockIdx.x*4 + w;
  int mt = gw >> 1, pair = gw & 1;
  const int nkc = 16;
  size_t ao  = ((size_t)mt*nkc)*512 + l*8;
  size_t b0o = ((size_t)(pair*2)*nkc)*512 + l*8;
  size_t b1o = b0o + (size_t)nkc*512;
  v16f acc0, acc1;
  #pragma unroll
  for (int i=0;i<16;i++){ acc0[i] = 0.f; acc1[i] = 0.f; }
  for (int kc=0; kc<nkc; kc++){
    v8s Ah  = *(const v8s*)(PH + ao);
    v8s Al  = *(const v8s*)(PL + ao);
    v8s B0h = *(const v8s*)(PWH + b0o);
    v8s B0l = *(const v8s*)(PWL + b0o);
    v8s B1h = *(const v8s*)(PWH + b1o);
    v8s B1l = *(const v8s*)(PWL + b1o);
    acc0 = __builtin_amdgcn_mfma_f32_32x32x16_bf16(Ah, B0h, acc0, 0, 0, 0);
    acc1 = __builtin_amdgcn_mfma_f32_32x32x16_bf16(Ah, B1h, acc1, 0, 0, 0);
    acc0 = __builtin_amdgcn_mfma_f32_32x32x16_bf16(Ah, B0l, acc0, 0, 0, 0);
    acc1 = __builtin_amdgcn_mfma_f32_32x32x16_bf16(Ah, B1l, acc1, 0, 0, 0);
    acc0 = __builtin_amdgcn_mfma_f32_32x32x16_bf16(Al, B0h, acc0, 0, 0, 0);
    acc1 = __builtin_amdgcn_mfma_f32_32x32x16_bf16(Al, B1h, acc1, 0, 0, 0);
    ao += 512; b0o += 512; b1o += 512;
  }
  int rbase = mt*32;
  int c0 = pair*64 + (l & 31), c1 = c0 + 32;
  float g0 = eg[c0]*INV_SQRT1P, g1 = eg[c1]*INV_SQRT1P;
  float bb0 = eb[c0], bb1 = eb[c1];
  #pragma unroll
  for (int r=0;r<16;r++){
    int rl_ = (r&3) + ((r>>2)<<3) + ((l>>5)<<2);
    float* dst = EMB + (size_t)(rbase + rl_)*128;
    dst[c0] = lrelu(g0*acc0[r] + bb0);
    dst[c1] = lrelu(g1*acc1[r] + bb1);
  }
}

// ---------------- edge epilogue body ----------------
static __device__ void edge_body(int bid, int tid, int (&js)[4][20],
    const float* __restrict__ Y, const int* __restrict__ idx,
    const float* __restrict__ g, const float* __restrict__ bias,
    float* __restrict__ out, int O, int ldo, int ooff){
  int rpb = 256/O;
  int rloc = tid/O;
  int o = tid - rloc*O;
  int row = bid*rpb + rloc;
  int b = row >> 10;
  int nj = rpb*20;
  if (tid < nj) js[tid/20][tid%20] = idx[(bid*rpb)*20 + tid];
  __syncthreads();
  int O2 = O*2;
  float y1c = Y[(size_t)row*O2 + o];
  float d   = Y[(size_t)row*O2 + O + o] - y1c;
  float sc  = g[o] * INV_SQRT1P;
  float bb  = bias[o];
  const float* Yb = Y + ((size_t)(b<<10))*O2;
  float best = -1e38f;
  #pragma unroll
  for (int k=0;k<20;k++){
    float f = sc * (Yb[(size_t)js[rloc][k]*O2 + o] + d) + bb;
    best = fmaxf(best, lrelu(f));
  }
  out[(size_t)row*ldo + ooff + o] = best;
}

__global__ __launch_bounds__(256) void k_edge2(
    const float* __restrict__ Ya, const int* __restrict__ idxA,
    const float* __restrict__ gA, const float* __restrict__ bA,
    float* __restrict__ outA, int OA, int ldoA, int ooffA, int ngridA,
    const float* __restrict__ Yb, const int* __restrict__ idxB,
    const float* __restrict__ gB, const float* __restrict__ bB,
    float* __restrict__ outB, int OB, int ldoB, int ooffB){
  __shared__ int js[4][20];
  int bid = (int)blockIdx.x;
  if (bid < ngridA)
    edge_body(bid, threadIdx.x, js, Ya, idxA, gA, bA, outA, OA, ldoA, ooffA);
  else
    edge_body(bid - ngridA, threadIdx.x, js, Yb, idxB, gB, bB, outB, OB, ldoB, ooffB);
}

// ---------------- attention (16 batches): fused mean + gc ----------------
__global__ __launch_bounds__(1024) void k_meangc(const float* __restrict__ emb,
     const float* __restrict__ att_w, float* __restrict__ gc){
  int b = blockIdx.x; int f = threadIdx.x & 127; int ny = threadIdx.x >> 7;
  const float* e = emb + ((size_t)(b<<10) + ny*128)*128 + f;
  float s = 0.f;
  for (int n=0;n<128;n++) s += e[n*128];
  __shared__ float red[8][128];
  __shared__ float mr[128];
  red[ny][f] = s;
  __syncthreads();
  if (ny == 0){
    float t = 0.f;
    #pragma unroll
    for (int i=0;i<8;i++) t += red[i][f];
    mr[f] = t * (1.0f/1024.0f);
  }
  __syncthreads();
  if (threadIdx.x < 128){
    int g = threadIdx.x;
    float s2 = 0.f;
    for (int ff=0; ff<128; ff++) s2 += mr[ff]*att_w[ff*128+g];
    gc[b*128+g] = tanhf(s2);
  }
}

// ---------------- sc: 4 rows per block (4 waves) ----------------
__global__ __launch_bounds__(256) void k_sc(const float* __restrict__ emb, const float* __restrict__ gc,
     float* __restrict__ sc, float* __restrict__ attout){
  int wave = threadIdx.x >> 6;
  int l = threadIdx.x & 63;
  int row = blockIdx.x*4 + wave;
  int b = row >> 10;
  const float* e  = emb + (size_t)row*128;
  const float* gb = gc + b*128;
  float p = e[l]*gb[l] + e[l+64]*gb[l+64];
  #pragma unroll
  for (int off=32; off>0; off>>=1) p += __shfl_xor(p, off, 64);
  if (l == 0){
    float s = 1.0f/(1.0f + expf(-p));
    sc[row] = s;
    attout[row] = s;
  }
}

__global__ __launch_bounds__(1024) void k_pool(const float* __restrict__ emb, const float* __restrict__ sc,
     float* __restrict__ ep){
  int b = blockIdx.x; int f = threadIdx.x & 127; int ny = threadIdx.x >> 7;
  const float* e  = emb + ((size_t)(b<<10) + ny*128)*128 + f;
  const float* sb = sc + (b<<10) + ny*128;
  float s = 0.f;
  for (int n=0;n<128;n++) s += e[n*128]*sb[n];
  __shared__ float red[8][128];
  red[ny][f] = s;
  __syncthreads();
  if (ny == 0){
    float t = 0.f;
    #pragma unroll
    for (int i=0;i<8;i++) t += red[i][f];
    ep[b*128+f] = t;
  }
}

// ---------------- tensor network scoring ----------------
__global__ __launch_bounds__(256) void k_tnet(const float* __restrict__ e1, const float* __restrict__ e2,
    const float* __restrict__ tn_w, const float* __restrict__ tn_wb, const float* __restrict__ tn_bias,
    float* __restrict__ tsout){
  int b = blockIdx.x; int t = threadIdx.x; int tt = t & 15; int fs = t >> 4;
  __shared__ float E1[128], E2[128], red[16][17];
  if (t < 128){ E1[t] = e1[b*128+t]; E2[t] = e2[b*128+t]; }
  __syncthreads();
  float acc = 0.f;
  for (int f = fs*8; f < fs*8+8; f++){
    const float* tw = tn_w + f*128*16 + tt;
    float partial = 0.f;
    for (int g=0; g<128; g++) partial += E2[g]*tw[g*16];
    acc += E1[f]*partial;
  }
  red[fs][tt] = acc;
  __syncthreads();
  if (t < 16){
    float s = 0.f;
    #pragma unroll
    for (int i=0;i<16;i++) s += red[i][t];
    float acc2 = 0.f;
    for (int c=0;c<128;c++) acc2 += tn_wb[t*256+c]*E1[c] + tn_wb[t*256+128+c]*E2[c];
    float v = s + acc2 + tn_bias[t];
    tsout[b*16+t] = v > 0.f ? v : 0.f;
  }
}

__global__ __launch_bounds__(128) void k_score2(const float* __restrict__ ts,
   const float* __restrict__ fc1_w, const float* __restrict__ fc1_b,
   const float* __restrict__ sc_w, const float* __restrict__ sc_b, float* __restrict__ out){
  int t = threadIdx.x; int b = t >> 4, i = t & 15;
  __shared__ float h2[8][17];
  float a = 0.f;
  #pragma unroll
  for (int k=0;k<16;k++) a += ts[b*16+k]*fc1_w[i*16+k];
  a += fc1_b[i];
  h2[b][i] = a > 0.f ? a : 0.f;
  __syncthreads();
  if (t < 8){
    float s = 0.f;
    #pragma unroll
    for (int k=0;k<16;k++) s += h2[t][k]*sc_w[k];
    s += sc_b[0];
    out[t] = 1.0f/(1.0f + expf(-s));
  }
}

extern "C" void kernel_launch(void* const* d_in, const int* in_sizes, int n_in,
                              void* d_out, int out_size, void* d_ws, size_t ws_size,
                              hipStream_t stream){
  const float* f1  = (const float*)d_in[0];
  const float* f2  = (const float*)d_in[1];
  const float* sw1 = (const float*)d_in[2];  const float* sg1 = (const float*)d_in[3];  const float* sb1 = (const float*)d_in[4];
  const float* fw1 = (const float*)d_in[5];  const float* fg1 = (const float*)d_in[6];  const float* fb1 = (const float*)d_in[7];
  const float* sw2 = (const float*)d_in[8];  const float* sg2 = (const float*)d_in[9];  const float* sb2 = (const float*)d_in[10];
  const float* fw2 = (const float*)d_in[11]; const float* fg2 = (const float*)d_in[12]; const float* fb2 = (const float*)d_in[13];
  const float* sw3 = (const float*)d_in[14]; const float* sg3 = (const float*)d_in[15]; const float* sb3 = (const float*)d_in[16];
  const float* fw3 = (const float*)d_in[17]; const float* fg3 = (const float*)d_in[18]; const float* fb3 = (const float*)d_in[19];
  const float* ew  = (const float*)d_in[20]; const float* eg  = (const float*)d_in[21]; const float* eb  = (const float*)d_in[22];
  const float* att_w   = (const float*)d_in[23];
  const float* tn_w    = (const float*)d_in[24];
  const float* tn_wb   = (const float*)d_in[25];
  const float* tn_bias = (const float*)d_in[26];
  const float* fc1_w   = (const float*)d_in[27];
  const float* fc1_b   = (const float*)d_in[28];
  const float* sc_w    = (const float*)d_in[29];
  const float* sc_b    = (const float*)d_in[30];

  float* W    = (float*)d_ws;
  float* Tx0  = W;                         // 1M (16384 x <=64)
  float* Tx1  = W + 1048576;               // 1M
  float* Ts0  = W + 2097152;               // 2M (16384 x 128)
  float* Ts1  = W + 4194304;               // 1M
  float* X3S3 = W + 5242880;               // 4M (16384 x 256)
  float* EMB  = W + 9437184;               // 2M
  float* xxA  = W + 11534336;              // 16384
  float* xxB  = W + 11550720;              // 16384
  float* gcb  = W + 11567104;              // 2048
  float* scb  = W + 11569152;              // 16384
  float* ep   = W + 11585536;              // 2048
  float* tsb  = W + 11587584;              // 128
  int*   idxA = (int*)(W + 11587712);      // 327680 ints
  int*   idxB = (int*)(W + 11915392);      // 327680 ints
  unsigned short* PHa  = (unsigned short*)(W + 12243072); // 1M floats
  unsigned short* PLa  = (unsigned short*)(W + 13291648);
  unsigned short* PHb  = (unsigned short*)(W + 14340224);
  unsigned short* PLb  = (unsigned short*)(W + 15388800);
  unsigned short* PWHa = (unsigned short*)(W + 16437376); // 16K floats
  unsigned short* PWLa = (unsigned short*)(W + 16453760);
  unsigned short* PWHb = (unsigned short*)(W + 16470144);
  unsigned short* PWLb = (unsigned short*)(W + 16486528);
  float* REGa = W + 16502912;              // 4M
  float* REGb = W + 20697216;              // 4M
  unsigned short* PH2 = (unsigned short*)(W + 24891520);  // 2M floats
  unsigned short* PL2 = (unsigned short*)(W + 26988672);  // 2M floats

  (void)ws_size;
  float* out = (float*)d_out;

  // merged two-path edge layer
  auto edge2 = [&](const float* xa, int CA, int OA, const float* wa,
                   const float* ga, const float* ba, float* xoutA, int ldoA, int ooffA,
                   const float* xb, int CB, int OB, const float* wb,
                   const float* gb, const float* bb, float* xoutB, int ldoB, int ooffB){
    int KpA = (CA + 15) & ~15, KpB = (CB + 15) & ~15;
    int nkcA = KpA >> 4,       nkcB = KpB >> 4;
    int npairA = 2*OA/64,      npairB = 2*OB/64;
    int nwblkA = ((2*OA/32)*nkcA*64 + 255)/256;
    int nwblkB = ((2*OB/32)*nkcB*64 + 255)/256;
    int nblkA  = nwblkA + 128*nkcA;
    int nblkB  = nwblkB + 128*nkcB;
    int nymfA  = 64*npairA, nymfB = 64*npairB;
    k_pw2<<<nblkA + nblkB, 256, 0, stream>>>(
        xa, PHa, PLa, xxA, wa, PWHa, PWLa, CA, KpA, OA, nwblkA, nblkA,
        xb, PHb, PLb, xxB, wb, PWHb, PWLb, CB, KpB, OB, nwblkB);
    k_dy2<<<(nymfA + 512) + (nymfB + 512), 512, 0, stream>>>(
        PHa, PLa, PWHa, PWLa, xxA, idxA, REGa, KpA, 2*OA, npairA, nymfA,
        PHb, PLb, PWHb, PWLb, xxB, idxB, REGb, KpB, 2*OB, npairB, nymfB);
    int ngridA = 16384/(256/OA);
    int ngridB = 16384/(256/OB);
    k_edge2<<<ngridA + ngridB, 256, 0, stream>>>(
        REGa, idxA, ga, ba, xoutA, OA, ldoA, ooffA, ngridA,
        REGb, idxB, gb, bb, xoutB, OB, ldoB, ooffB);
  };

  // extracts (independent)
  k_ext3<<<(2*8*3*1024+255)/256, 256, 0, stream>>>(f1, f2, Tx0);
  k_extT<<<1024, 256, 0, stream>>>(f1, f2, Ts0);
  // three merged layers (xyz path = A, sem path = B)
  edge2(Tx0, 3,   64, sw1, sg1, sb1, Tx1, 64, 0,
        Ts0, 128, 64, fw1, fg1, fb1, Ts1, 64, 0);
  edge2(Tx1, 64,  64, sw2, sg2, sb2, Tx0, 64, 0,
        Ts1, 64,  64, fw2, fg2, fb2, Ts0, 64, 0);
  edge2(Tx0, 64, 128, sw3, sg3, sb3, X3S3, 256, 0,
        Ts0, 64, 128, fw3, fg3, fb3, X3S3, 256, 128);
  // combine via MFMA: pack X3S3 (K=256) + ew (128x256 plain), then GEMM+epilogue
  {
    int nwblk = ((128/32)*16*64 + 255)/256;          // 16
    k_pw<<<nwblk + 128*16, 256, 0, stream>>>(X3S3, PH2, PL2, xxA, ew, PWHa, PWLa,
        256, 256, 128, nwblk, 128, 0, 0);
    k_emb<<<256, 256, 0, stream>>>(PH2, PL2, PWHa, PWLa, eg, eb, EMB);
  }
  // attention over all 16 batches
  k_meangc<<<16, 1024, 0, stream>>>(EMB, att_w, gcb);
  k_sc<<<4096, 256, 0, stream>>>(EMB, gcb, scb, out + 8);
  k_pool<<<16, 1024, 0, stream>>>(EMB, scb, ep);

  k_tnet<<<8, 256, 0, stream>>>(ep, ep + 1024, tn_w, tn_wb, tn_bias, tsb);
  k_score2<<<1, 128, 0, stream>>>(tsb, fc1_w, fc1_b, sc_w, sc_b, out);
}

// Round 12
// 455.257 us; speedup vs baseline: 1.2607x; 1.2607x over previous
//
#include <hip/hip_runtime.h>
#include <math.h>

#define INV_SQRT1P 0.99999500003749968754f   // 1/sqrt(1+1e-5)

typedef short v8s  __attribute__((ext_vector_type(8)));
typedef float v16f __attribute__((ext_vector_type(16)));

static __device__ __forceinline__ float lrelu(float f){ return f >= 0.0f ? f : 0.2f*f; }

static __device__ __forceinline__ int lanecnt_below(unsigned long long m){
  int c = __builtin_amdgcn_mbcnt_lo((unsigned)m, 0u);
  return __builtin_amdgcn_mbcnt_hi((unsigned)(m >> 32), c);
}

// ---------------- extract xyz (C=3) for BOTH inputs in one launch ----------------
__global__ void k_ext3(const float* __restrict__ f1, const float* __restrict__ f2,
                       float* __restrict__ out){
  int i = blockIdx.x*256 + threadIdx.x;
  int half = 8*3*1024;
  if (i >= 2*half) return;
  const float* f = (i < half) ? f1 : f2;
  int boff = (i < half) ? 0 : 8;
  int ii = (i < half) ? i : i - half;
  int n  = ii & 1023;
  int bc = ii >> 10;
  int c  = bc % 3;
  int b  = bc / 3;
  out[((size_t)(((b+boff)<<10)+n))*3 + c] = f[((size_t)(b*131 + c) << 10) + n];
}

// ---------------- extract sem (C=128) via LDS tile transpose, both inputs ----------
__global__ __launch_bounds__(256) void k_extT(const float* __restrict__ f1,
    const float* __restrict__ f2, float* __restrict__ out){
  __shared__ float T[32][65];
  int bid = blockIdx.x;              // 16 ntile x 4 ctile x 16 (input*8+b)
  int nt = bid & 15;
  int ct = (bid >> 4) & 3;
  int bb = bid >> 6;                 // 0..15
  const float* f = (bb < 8) ? f1 : f2;
  int b = bb & 7;
  int tid = threadIdx.x;
  #pragma unroll
  for (int it=0; it<8; it++){
    int cc = it*4 + (tid >> 6);      // 0..31
    int nn = tid & 63;
    T[cc][nn] = f[((size_t)(b*131 + 3 + ct*32 + cc) << 10) + nt*64 + nn];
  }
  __syncthreads();
  size_t rowb = ((size_t)bb << 10) + nt*64;
  #pragma unroll
  for (int it=0; it<8; it++){
    int nn = it*8 + (tid >> 5);      // 0..63
    int c  = tid & 31;
    out[(rowb + nn)*128 + ct*32 + c] = T[c][nn];
  }
}

// ---------------- pack body (wpack blocks first, then X-pack blocks) ----------------
static __device__ __forceinline__ void pw_body(int bid, int tid,
    const float* __restrict__ X, unsigned short* __restrict__ PH,
    unsigned short* __restrict__ PL, float* __restrict__ xxout,
    const float* __restrict__ Wm, unsigned short* __restrict__ PWH,
    unsigned short* __restrict__ PWL,
    int C, int Kp, int O, int nwblk, int nrowsB, int wsplit, int doxx){
  int nkc = Kp >> 4;
  if (bid < nwblk){
    int gid = bid*256 + tid;
    int nchunk = (nrowsB/32)*nkc;
    if (gid >= nchunk*64) return;
    int lane = gid & 63;
    int chunk = gid >> 6;
    int jb = chunk / nkc, kc = chunk - jb*nkc;
    int j = jb*32 + (lane & 31);
    int k0 = kc*16 + ((lane>>5)<<3);
    unsigned short h[8], lo[8];
    #pragma unroll
    for (int t=0;t<8;t++){
      int k = k0 + t;
      float x = 0.f;
      if (k < C){
        if (wsplit) x = (j < O) ? Wm[(size_t)j*2*C + k] : Wm[(size_t)(j-O)*2*C + C + k];
        else        x = Wm[(size_t)j*C + k];
      }
      unsigned u = __float_as_uint(x);
      unsigned h16 = (u + 0x7fffu + ((u>>16)&1u)) >> 16;
      float hf = __uint_as_float(h16 << 16);
      float lf = x - hf;
      unsigned ul = __float_as_uint(lf);
      unsigned l16 = (ul + 0x7fffu + ((ul>>16)&1u)) >> 16;
      h[t] = (unsigned short)h16; lo[t] = (unsigned short)l16;
    }
    size_t o = (size_t)chunk*512 + lane*8;
    *(v8s*)(PWH + o) = *(v8s*)h;
    *(v8s*)(PWL + o) = *(v8s*)lo;
  } else {
    int gid = (bid - nwblk)*256 + tid;      // grid exact: 512*nkc*64 threads
    int lane = gid & 63;
    int chunk = gid >> 6;
    int rb = chunk / nkc, kc = chunk - rb*nkc;
    int row = rb*32 + (lane & 31);
    int k0 = kc*16 + ((lane>>5)<<3);
    unsigned short h[8], lo[8];
    const float* Xr = X + (size_t)row*C;
    #pragma unroll
    for (int j=0;j<8;j++){
      int k = k0 + j;
      float x = (k < C) ? Xr[k] : 0.f;
      unsigned u = __float_as_uint(x);
      unsigned h16 = (u + 0x7fffu + ((u>>16)&1u)) >> 16;
      float hf = __uint_as_float(h16 << 16);
      float lf = x - hf;
      unsigned ul = __float_as_uint(lf);
      unsigned l16 = (ul + 0x7fffu + ((ul>>16)&1u)) >> 16;
      h[j] = (unsigned short)h16; lo[j] = (unsigned short)l16;
    }
    size_t o = (size_t)chunk*512 + lane*8;
    *(v8s*)(PH + o) = *(v8s*)h;
    *(v8s*)(PL + o) = *(v8s*)lo;
    if (doxx && kc == 0 && (lane & 32) == 0){
      float s = 0.f;
      for (int c=0;c<C;c++) s += Xr[c]*Xr[c];    // ascending order == old k_xx
      xxout[row] = s;
    }
  }
}

// merged pack for two independent paths — single call site via pointer select
__global__ __launch_bounds__(256) void k_pw2(
    const float* __restrict__ XA, unsigned short* __restrict__ PHa,
    unsigned short* __restrict__ PLa, float* __restrict__ xxA,
    const float* __restrict__ WA, unsigned short* __restrict__ PWHa,
    unsigned short* __restrict__ PWLa, int CA, int KpA, int OA, int nwblkA, int nblkA,
    const float* __restrict__ XB, unsigned short* __restrict__ PHb,
    unsigned short* __restrict__ PLb, float* __restrict__ xxB,
    const float* __restrict__ WB, unsigned short* __restrict__ PWHb,
    unsigned short* __restrict__ PWLb, int CB, int KpB, int OB, int nwblkB){
  int bid = blockIdx.x;
  bool isA = bid < nblkA;
  const float* X = isA ? XA : XB;
  unsigned short* PH = isA ? PHa : PHb;
  unsigned short* PL = isA ? PLa : PLb;
  float* xxo = isA ? xxA : xxB;
  const float* Wm = isA ? WA : WB;
  unsigned short* PWH = isA ? PWHa : PWHb;
  unsigned short* PWL = isA ? PWLa : PWLb;
  int C = isA ? CA : CB, Kp = isA ? KpA : KpB, O = isA ? OA : OB;
  int nwblk = isA ? nwblkA : nwblkB;
  int lb = isA ? bid : bid - nblkA;
  pw_body(lb, threadIdx.x, X, PH, PL, xxo, Wm, PWH, PWL, C, Kp, O, nwblk, 2*O, 1, 1);
}

// single pack (emb combine)
__global__ __launch_bounds__(256) void k_pw(const float* __restrict__ X,
    unsigned short* __restrict__ PH, unsigned short* __restrict__ PL,
    float* __restrict__ xxout, const float* __restrict__ Wm,
    unsigned short* __restrict__ PWH, unsigned short* __restrict__ PWL,
    int C, int Kp, int O, int nwblk, int nrowsB, int wsplit, int doxx){
  pw_body(blockIdx.x, threadIdx.x, X, PH, PL, xxout, Wm, PWH, PWL,
          C, Kp, O, nwblk, nrowsB, wsplit, doxx);
}

// ---------------- ymf body: Y = X.Wp^T tile per wave ----------------
static __device__ __forceinline__ void ymf_body(int gw, int l,
    const unsigned short* __restrict__ PH, const unsigned short* __restrict__ PL,
    const unsigned short* __restrict__ PWH, const unsigned short* __restrict__ PWL,
    float* __restrict__ Y, int nkc, int N, int npair){
  int mt = gw / npair;
  int pair = gw - mt*npair;
  int jb0 = pair*2, jb1 = pair*2 + 1;
  size_t ao  = ((size_t)mt*nkc)*512 + l*8;
  size_t b0o = ((size_t)jb0*nkc)*512 + l*8;
  size_t b1o = ((size_t)jb1*nkc)*512 + l*8;
  v16f acc0, acc1;
  #pragma unroll
  for (int i=0;i<16;i++){ acc0[i] = 0.f; acc1[i] = 0.f; }
  for (int kc=0; kc<nkc; kc++){
    v8s Ah  = *(const v8s*)(PH + ao);
    v8s Al  = *(const v8s*)(PL + ao);
    v8s B0h = *(const v8s*)(PWH + b0o);
    v8s B0l = *(const v8s*)(PWL + b0o);
    v8s B1h = *(const v8s*)(PWH + b1o);
    v8s B1l = *(const v8s*)(PWL + b1o);
    acc0 = __builtin_amdgcn_mfma_f32_32x32x16_bf16(Ah, B0h, acc0, 0, 0, 0);
    acc1 = __builtin_amdgcn_mfma_f32_32x32x16_bf16(Ah, B1h, acc1, 0, 0, 0);
    acc0 = __builtin_amdgcn_mfma_f32_32x32x16_bf16(Ah, B0l, acc0, 0, 0, 0);
    acc1 = __builtin_amdgcn_mfma_f32_32x32x16_bf16(Ah, B1l, acc1, 0, 0, 0);
    acc0 = __builtin_amdgcn_mfma_f32_32x32x16_bf16(Al, B0h, acc0, 0, 0, 0);
    acc1 = __builtin_amdgcn_mfma_f32_32x32x16_bf16(Al, B1h, acc1, 0, 0, 0);
    ao += 512; b0o += 512; b1o += 512;
  }
  int rbase = mt*32;
  int c0 = pair*64 + (l & 31), c1 = c0 + 32;
  #pragma unroll
  for (int r=0;r<16;r++){
    int rl_ = (r&3) + ((r>>2)<<3) + ((l>>5)<<2);
    float* dst = Y + (size_t)(rbase + rl_)*N;
    dst[c0] = acc0[r];
    dst[c1] = acc1[r];
  }
}

// ---------------- dtk body: distances + exact top-20 for rowblock rb ----------------
static __device__ __forceinline__ void dtk_body(float (&Sl)[16][1024], int t, int wave, int l,
    const unsigned short* __restrict__ PH, const unsigned short* __restrict__ PL,
    const float* __restrict__ xx, int* __restrict__ idx, int nkc){
  int rb = ((t & 7) << 6) | (t >> 3);   // XCD swizzle over 512 dtk blocks
  int batch = rb >> 5;
  const float* xxb = xx + (batch<<10);
  int rbase_local = (rb & 31)*32;

  v16f acc[4];
  #pragma unroll
  for (int i=0;i<4;i++){
    #pragma unroll
    for (int j=0;j<16;j++) acc[i][j] = 0.f;
  }
  #pragma unroll
  for (int pp=0; pp<2; pp++){
    int pair = wave*2 + pp;
    size_t a   = ((size_t)rb*nkc)*512 + l*8;
    size_t b0o = ((size_t)(batch*32 + 2*pair)*nkc)*512 + l*8;
    size_t b1o = b0o + (size_t)nkc*512;
    for (int kc=0; kc<nkc; kc++){
      v8s Ah  = *(const v8s*)(PH + a);
      v8s Al  = *(const v8s*)(PL + a);
      v8s B0h = *(const v8s*)(PH + b0o);
      v8s B0l = *(const v8s*)(PL + b0o);
      v8s B1h = *(const v8s*)(PH + b1o);
      v8s B1l = *(const v8s*)(PL + b1o);
      acc[2*pp]   = __builtin_amdgcn_mfma_f32_32x32x16_bf16(Ah, B0h, acc[2*pp],   0, 0, 0);
      acc[2*pp+1] = __builtin_amdgcn_mfma_f32_32x32x16_bf16(Ah, B1h, acc[2*pp+1], 0, 0, 0);
      acc[2*pp]   = __builtin_amdgcn_mfma_f32_32x32x16_bf16(Ah, B0l, acc[2*pp],   0, 0, 0);
      acc[2*pp+1] = __builtin_amdgcn_mfma_f32_32x32x16_bf16(Ah, B1l, acc[2*pp+1], 0, 0, 0);
      acc[2*pp]   = __builtin_amdgcn_mfma_f32_32x32x16_bf16(Al, B0h, acc[2*pp],   0, 0, 0);
      acc[2*pp+1] = __builtin_amdgcn_mfma_f32_32x32x16_bf16(Al, B1h, acc[2*pp+1], 0, 0, 0);
      a += 512; b0o += 512; b1o += 512;
    }
  }

  #pragma unroll
  for (int h=0; h<2; h++){
    #pragma unroll
    for (int pp=0; pp<2; pp++){
      int pair = wave*2 + pp;
      int c0 = pair*64 + (l & 31), c1 = c0 + 32;
      float xc0 = xxb[c0], xc1 = xxb[c1];
      #pragma unroll
      for (int r = 0; r < 8; r++){
        int rr = h*8 + r;
        int rl = (rr&3) + (((rr>>2)&1)<<3) + ((l>>5)<<2);  // 0..15
        float xr = xxb[rbase_local + h*16 + rl];
        Sl[rl][c0] = 2.f*acc[2*pp][rr]   - xr - xc0;
        Sl[rl][c1] = 2.f*acc[2*pp+1][rr] - xr - xc1;
      }
    }
    __syncthreads();
    {
      int hi = l >> 5;
      int li = l & 31;
      int rloc = wave*2 + hi;
      int grow = rb*32 + h*16 + rloc;
      int out_base = grow*20;
      unsigned long long hm = hi ? 0xFFFFFFFF00000000ull : 0x00000000FFFFFFFFull;

      unsigned kv[32];
      #pragma unroll
      for (int j=0;j<32;j++){
        unsigned u = __float_as_uint(Sl[rloc][li + 32*j]);
        kv[j] = (u & 0x80000000u) ? ~u : (u | 0x80000000u);
      }

      unsigned lmax = kv[0];
      #pragma unroll
      for (int j=1;j<32;j++) lmax = lmax > kv[j] ? lmax : kv[j];

      unsigned tau = 0u;
      #pragma unroll
      for (int bit=31; bit>=0; --bit){
        unsigned cand = tau | (1u << bit);
        unsigned long long M = __ballot(lmax >= cand);
        int c = hi ? __popc((unsigned)(M >> 32)) : __popc((unsigned)M);
        tau = (c >= 20) ? cand : tau;
      }

      unsigned long long* sl = (unsigned long long*)&Sl[rloc][0];
      sl[li] = 0ull; sl[li+32] = 0ull;
      int b2 = 0;
      #pragma unroll
      for (int j=0;j<32;j++){
        bool p = kv[j] >= tau;
        unsigned long long M = __ballot(p) & hm;
        if (p){
          int s = b2 + lanecnt_below(M);
          if (s < 64) sl[s] = ((unsigned long long)kv[j] << 32) | (unsigned)(li + 32*j);
        }
        b2 += __popcll(M);
      }

      if (b2 <= 64){
        unsigned long long pk0 = sl[li], pk1 = sl[li+32];
        unsigned vcur = 0u;
        #pragma unroll
        for (int bit=31; bit>=0; --bit){
          unsigned long long cc = (unsigned long long)(vcur | (1u << bit)) << 32;
          unsigned long long B0 = __ballot(pk0 >= cc);
          unsigned long long B1 = __ballot(pk1 >= cc);
          int clo = __popc((unsigned)B0) + __popc((unsigned)B1);
          int chi = __popc((unsigned)(B0>>32)) + __popc((unsigned)(B1>>32));
          int c = hi ? chi : clo;
          vcur = (c >= 20) ? (vcur | (1u << bit)) : vcur;
        }
        unsigned k0 = (unsigned)(pk0 >> 32), k1 = (unsigned)(pk1 >> 32);
        unsigned long long G0 = __ballot(k0 > vcur) & hm;
        unsigned long long G1 = __ballot(k1 > vcur) & hm;
        int ng0 = __popcll(G0);
        int c1  = ng0 + __popcll(G1);
        if (k0 > vcur) idx[out_base + lanecnt_below(G0)] = (int)(pk0 & 0xffffffffu);
        if (k1 > vcur) idx[out_base + ng0 + lanecnt_below(G1)] = (int)(pk1 & 0xffffffffu);
        unsigned long long E0 = __ballot(k0 == vcur) & hm;
        unsigned long long E1 = __ballot(k1 == vcur) & hm;
        int ne0 = __popcll(E0);
        if (k0 == vcur){ int s = c1 + lanecnt_below(E0); if (s < 20) idx[out_base + s] = (int)(pk0 & 0xffffffffu); }
        if (k1 == vcur){ int s = c1 + ne0 + lanecnt_below(E1); if (s < 20) idx[out_base + s] = (int)(pk1 & 0xffffffffu); }
      } else {
        unsigned cur = 0u;
        #pragma unroll 1
        for (int bit=31; bit>=0; --bit){
          unsigned cand = cur | (1u << bit);
          int lc = 0;
          #pragma unroll
          for (int j=0;j<32;j++) lc += (kv[j] >= cand) ? 1 : 0;
          #pragma unroll
          for (int off=1; off<32; off<<=1) lc += __shfl_xor(lc, off, 64);
          cur = (lc >= 20) ? cand : cur;
        }
        int bse = 0;
        #pragma unroll 1
        for (int j=0;j<32;j++){
          unsigned long long Mg = __ballot(kv[j] > cur) & hm;
          if (kv[j] > cur){ int s = bse + lanecnt_below(Mg); idx[out_base + s] = li + 32*j; }
          bse += __popcll(Mg);
        }
        #pragma unroll 1
        for (int j=0;j<32;j++){
          unsigned long long Me = __ballot(kv[j] == cur) & hm;
          if (kv[j] == cur){ int s = bse + lanecnt_below(Me); if (s < 20) idx[out_base + s] = li + 32*j; }
          bse += __popcll(Me);
          if (bse >= 20) break;
        }
      }
    }
    __syncthreads();
  }
}

// merged Y-GEMM + distance/top-20 for TWO independent paths.
// Single call site per body: per-path pointers/params selected up front
// (nymfA == nymfB always: npair depends only on O, same O both paths).
__global__ __launch_bounds__(512) void k_dy2(
    const unsigned short* __restrict__ PHa, const unsigned short* __restrict__ PLa,
    const unsigned short* __restrict__ PWHa, const unsigned short* __restrict__ PWLa,
    const float* __restrict__ xxA, int* __restrict__ idxA, float* __restrict__ Ya,
    int KpA, int NA, int npairA, int nymfA,
    const unsigned short* __restrict__ PHb, const unsigned short* __restrict__ PLb,
    const unsigned short* __restrict__ PWHb, const unsigned short* __restrict__ PWLb,
    const float* __restrict__ xxB, int* __restrict__ idxB, float* __restrict__ Yb,
    int KpB, int NB, int npairB, int nymfB){
  __shared__ float Sl[16][1024];          // 64 KB
  int wave = threadIdx.x >> 6;
  int l = threadIdx.x & 63;
  int bid = (int)blockIdx.x;
  int nblkA = nymfA + 512;
  bool isA = bid < nblkA;
  const unsigned short* PH  = isA ? PHa  : PHb;
  const unsigned short* PL  = isA ? PLa  : PLb;
  const unsigned short* PWH = isA ? PWHa : PWHb;
  const unsigned short* PWL = isA ? PWLa : PWLb;
  const float* xx = isA ? xxA : xxB;
  int* idx  = isA ? idxA : idxB;
  float* Y  = isA ? Ya : Yb;
  int Kp    = isA ? KpA : KpB;
  int N     = isA ? NA  : NB;
  int npair = isA ? npairA : npairB;
  int nymf  = isA ? nymfA  : nymfB;
  int lb    = isA ? bid : bid - nblkA;
  if (lb < nymf)
    ymf_body(lb*8 + wave, l, PH, PL, PWH, PWL, Y, Kp >> 4, N, npair);
  else
    dtk_body(Sl, lb - nymf, wave, l, PH, PL, xx, idx, Kp >> 4);
}

// ---------------- EMB combine via MFMA: EMB = lrelu(eg*(X3S3.ew^T)*inv + eb) --------
__global__ __launch_bounds__(256) void k_emb(const unsigned short* __restrict__ PH,
    const unsigned short* __restrict__ PL, const unsigned short* __restrict__ PWH,
    const unsigned short* __restrict__ PWL, const float* __restrict__ eg,
    const float* __restrict__ eb, float* __restrict__ EMB){
  int w = threadIdx.x >> 6;
  int l = threadIdx.x & 63;
  int gw = blockIdx.x*4 + w;
  int mt = gw >> 1, pair = gw & 1;
  const int nkc = 16;
  size_t ao  = ((size_t)mt*nkc)*512 + l*8;
  size_t b0o = ((size_t)(pair*2)*nkc)*512 + l*8;
  size_t b1o = b0o + (size_t)nkc*512;
  v16f acc0, acc1;
  #pragma unroll
  for (int i=0;i<16;i++){ acc0[i] = 0.f; acc1[i] = 0.f; }
  for (int kc=0; kc<nkc; kc++){
    v8s Ah  = *(const v8s*)(PH + ao);
    v8s Al  = *(const v8s*)(PL + ao);
    v8s B0h = *(const v8s*)(PWH + b0o);
    v8s B0l = *(const v8s*)(PWL + b0o);
    v8s B1h = *(const v8s*)(PWH + b1o);
    v8s B1l = *(const v8s*)(PWL + b1o);
    acc0 = __builtin_amdgcn_mfma_f32_32x32x16_bf16(Ah, B0h, acc0, 0, 0, 0);
    acc1 = __builtin_amdgcn_mfma_f32_32x32x16_bf16(Ah, B1h, acc1, 0, 0, 0);
    acc0 = __builtin_amdgcn_mfma_f32_32x32x16_bf16(Ah, B0l, acc0, 0, 0, 0);
    acc1 = __builtin_amdgcn_mfma_f32_32x32x16_bf16(Ah, B1l, acc1, 0, 0, 0);
    acc0 = __builtin_amdgcn_mfma_f32_32x32x16_bf16(Al, B0h, acc0, 0, 0, 0);
    acc1 = __builtin_amdgcn_mfma_f32_32x32x16_bf16(Al, B1h, acc1, 0, 0, 0);
    ao += 512; b0o += 512; b1o += 512;
  }
  int rbase = mt*32;
  int c0 = pair*64 + (l & 31), c1 = c0 + 32;
  float g0 = eg[c0]*INV_SQRT1P, g1 = eg[c1]*INV_SQRT1P;
  float bb0 = eb[c0], bb1 = eb[c1];
  #pragma unroll
  for (int r=0;r<16;r++){
    int rl_ = (r&3) + ((r>>2)<<3) + ((l>>5)<<2);
    float* dst = EMB + (size_t)(rbase + rl_)*128;
    dst[c0] = lrelu(g0*acc0[r] + bb0);
    dst[c1] = lrelu(g1*acc1[r] + bb1);
  }
}

// ---------------- edge epilogue body ----------------
static __device__ __forceinline__ void edge_body(int bid, int tid, int (&js)[4][20],
    const float* __restrict__ Y, const int* __restrict__ idx,
    const float* __restrict__ g, const float* __restrict__ bias,
    float* __restrict__ out, int O, int ldo, int ooff){
  int rpb = 256/O;
  int rloc = tid/O;
  int o = tid - rloc*O;
  int row = bid*rpb + rloc;
  int b = row >> 10;
  int nj = rpb*20;
  if (tid < nj) js[tid/20][tid%20] = idx[(bid*rpb)*20 + tid];
  __syncthreads();
  int O2 = O*2;
  float y1c = Y[(size_t)row*O2 + o];
  float d   = Y[(size_t)row*O2 + O + o] - y1c;
  float sc  = g[o] * INV_SQRT1P;
  float bb  = bias[o];
  const float* Yb = Y + ((size_t)(b<<10))*O2;
  float best = -1e38f;
  #pragma unroll
  for (int k=0;k<20;k++){
    float f = sc * (Yb[(size_t)js[rloc][k]*O2 + o] + d) + bb;
    best = fmaxf(best, lrelu(f));
  }
  out[(size_t)row*ldo + ooff + o] = best;
}

__global__ __launch_bounds__(256) void k_edge2(
    const float* __restrict__ Ya, const int* __restrict__ idxA,
    const float* __restrict__ gA, const float* __restrict__ bA,
    float* __restrict__ outA, int OA, int ldoA, int ooffA, int ngridA,
    const float* __restrict__ Yb, const int* __restrict__ idxB,
    const float* __restrict__ gB, const float* __restrict__ bB,
    float* __restrict__ outB, int OB, int ldoB, int ooffB){
  __shared__ int js[4][20];
  int bid = (int)blockIdx.x;
  bool isA = bid < ngridA;
  const float* Y = isA ? Ya : Yb;
  const int* idx = isA ? idxA : idxB;
  const float* g = isA ? gA : gB;
  const float* bb = isA ? bA : bB;
  float* o = isA ? outA : outB;
  int O = isA ? OA : OB, ldo = isA ? ldoA : ldoB, ooff = isA ? ooffA : ooffB;
  int lb = isA ? bid : bid - ngridA;
  edge_body(lb, threadIdx.x, js, Y, idx, g, bb, o, O, ldo, ooff);
}

// ---------------- attention (16 batches): fused mean + gc ----------------
__global__ __launch_bounds__(1024) void k_meangc(const float* __restrict__ emb,
     const float* __restrict__ att_w, float* __restrict__ gc){
  int b = blockIdx.x; int f = threadIdx.x & 127; int ny = threadIdx.x >> 7;
  const float* e = emb + ((size_t)(b<<10) + ny*128)*128 + f;
  float s = 0.f;
  for (int n=0;n<128;n++) s += e[n*128];
  __shared__ float red[8][128];
  __shared__ float mr[128];
  red[ny][f] = s;
  __syncthreads();
  if (ny == 0){
    float t = 0.f;
    #pragma unroll
    for (int i=0;i<8;i++) t += red[i][f];
    mr[f] = t * (1.0f/1024.0f);
  }
  __syncthreads();
  if (threadIdx.x < 128){
    int g = threadIdx.x;
    float s2 = 0.f;
    for (int ff=0; ff<128; ff++) s2 += mr[ff]*att_w[ff*128+g];
    gc[b*128+g] = tanhf(s2);
  }
}

// ---------------- sc: 4 rows per block (4 waves) ----------------
__global__ __launch_bounds__(256) void k_sc(const float* __restrict__ emb, const float* __restrict__ gc,
     float* __restrict__ sc, float* __restrict__ attout){
  int wave = threadIdx.x >> 6;
  int l = threadIdx.x & 63;
  int row = blockIdx.x*4 + wave;
  int b = row >> 10;
  const float* e  = emb + (size_t)row*128;
  const float* gb = gc + b*128;
  float p = e[l]*gb[l] + e[l+64]*gb[l+64];
  #pragma unroll
  for (int off=32; off>0; off>>=1) p += __shfl_xor(p, off, 64);
  if (l == 0){
    float s = 1.0f/(1.0f + expf(-p));
    sc[row] = s;
    attout[row] = s;
  }
}

__global__ __launch_bounds__(1024) void k_pool(const float* __restrict__ emb, const float* __restrict__ sc,
     float* __restrict__ ep){
  int b = blockIdx.x; int f = threadIdx.x & 127; int ny = threadIdx.x >> 7;
  const float* e  = emb + ((size_t)(b<<10) + ny*128)*128 + f;
  const float* sb = sc + (b<<10) + ny*128;
  float s = 0.f;
  for (int n=0;n<128;n++) s += e[n*128]*sb[n];
  __shared__ float red[8][128];
  red[ny][f] = s;
  __syncthreads();
  if (ny == 0){
    float t = 0.f;
    #pragma unroll
    for (int i=0;i<8;i++) t += red[i][f];
    ep[b*128+f] = t;
  }
}

// ---------------- tensor network scoring ----------------
__global__ __launch_bounds__(256) void k_tnet(const float* __restrict__ e1, const float* __restrict__ e2,
    const float* __restrict__ tn_w, const float* __restrict__ tn_wb, const float* __restrict__ tn_bias,
    float* __restrict__ tsout){
  int b = blockIdx.x; int t = threadIdx.x; int tt = t & 15; int fs = t >> 4;
  __shared__ float E1[128], E2[128], red[16][17];
  if (t < 128){ E1[t] = e1[b*128+t]; E2[t] = e2[b*128+t]; }
  __syncthreads();
  float acc = 0.f;
  for (int f = fs*8; f < fs*8+8; f++){
    const float* tw = tn_w + f*128*16 + tt;
    float partial = 0.f;
    for (int g=0; g<128; g++) partial += E2[g]*tw[g*16];
    acc += E1[f]*partial;
  }
  red[fs][tt] = acc;
  __syncthreads();
  if (t < 16){
    float s = 0.f;
    #pragma unroll
    for (int i=0;i<16;i++) s += red[i][t];
    float acc2 = 0.f;
    for (int c=0;c<128;c++) acc2 += tn_wb[t*256+c]*E1[c] + tn_wb[t*256+128+c]*E2[c];
    float v = s + acc2 + tn_bias[t];
    tsout[b*16+t] = v > 0.f ? v : 0.f;
  }
}

__global__ __launch_bounds__(128) void k_score2(const float* __restrict__ ts,
   const float* __restrict__ fc1_w, const float* __restrict__ fc1_b,
   const float* __restrict__ sc_w, const float* __restrict__ sc_b, float* __restrict__ out){
  int t = threadIdx.x; int b = t >> 4, i = t & 15;
  __shared__ float h2[8][17];
  float a = 0.f;
  #pragma unroll
  for (int k=0;k<16;k++) a += ts[b*16+k]*fc1_w[i*16+k];
  a += fc1_b[i];
  h2[b][i] = a > 0.f ? a : 0.f;
  __syncthreads();
  if (t < 8){
    float s = 0.f;
    #pragma unroll
    for (int k=0;k<16;k++) s += h2[t][k]*sc_w[k];
    s += sc_b[0];
    out[t] = 1.0f/(1.0f + expf(-s));
  }
}

extern "C" void kernel_launch(void* const* d_in, const int* in_sizes, int n_in,
                              void* d_out, int out_size, void* d_ws, size_t ws_size,
                              hipStream_t stream){
  const float* f1  = (const float*)d_in[0];
  const float* f2  = (const float*)d_in[1];
  const float* sw1 = (const float*)d_in[2];  const float* sg1 = (const float*)d_in[3];  const float* sb1 = (const float*)d_in[4];
  const float* fw1 = (const float*)d_in[5];  const float* fg1 = (const float*)d_in[6];  const float* fb1 = (const float*)d_in[7];
  const float* sw2 = (const float*)d_in[8];  const float* sg2 = (const float*)d_in[9];  const float* sb2 = (const float*)d_in[10];
  const float* fw2 = (const float*)d_in[11]; const float* fg2 = (const float*)d_in[12]; const float* fb2 = (const float*)d_in[13];
  const float* sw3 = (const float*)d_in[14]; const float* sg3 = (const float*)d_in[15]; const float* sb3 = (const float*)d_in[16];
  const float* fw3 = (const float*)d_in[17]; const float* fg3 = (const float*)d_in[18]; const float* fb3 = (const float*)d_in[19];
  const float* ew  = (const float*)d_in[20]; const float* eg  = (const float*)d_in[21]; const float* eb  = (const float*)d_in[22];
  const float* att_w   = (const float*)d_in[23];
  const float* tn_w    = (const float*)d_in[24];
  const float* tn_wb   = (const float*)d_in[25];
  const float* tn_bias = (const float*)d_in[26];
  const float* fc1_w   = (const float*)d_in[27];
  const float* fc1_b   = (const float*)d_in[28];
  const float* sc_w    = (const float*)d_in[29];
  const float* sc_b    = (const float*)d_in[30];

  float* W    = (float*)d_ws;
  float* Tx0  = W;                         // 1M (16384 x <=64)
  float* Tx1  = W + 1048576;               // 1M
  float* Ts0  = W + 2097152;               // 2M (16384 x 128)
  float* Ts1  = W + 4194304;               // 1M
  float* X3S3 = W + 5242880;               // 4M (16384 x 256)
  float* EMB  = W + 9437184;               // 2M
  float* xxA  = W + 11534336;              // 16384
  float* xxB  = W + 11550720;              // 16384
  float* gcb  = W + 11567104;              // 2048
  float* scb  = W + 11569152;              // 16384
  float* ep   = W + 11585536;              // 2048
  float* tsb  = W + 11587584;              // 128
  int*   idxA = (int*)(W + 11587712);      // 327680 ints
  int*   idxB = (int*)(W + 11915392);      // 327680 ints
  unsigned short* PHa  = (unsigned short*)(W + 12243072); // 1M floats
  unsigned short* PLa  = (unsigned short*)(W + 13291648);
  unsigned short* PHb  = (unsigned short*)(W + 14340224);
  unsigned short* PLb  = (unsigned short*)(W + 15388800);
  unsigned short* PWHa = (unsigned short*)(W + 16437376); // 16K floats
  unsigned short* PWLa = (unsigned short*)(W + 16453760);
  unsigned short* PWHb = (unsigned short*)(W + 16470144);
  unsigned short* PWLb = (unsigned short*)(W + 16486528);
  float* REGa = W + 16502912;              // 4M
  float* REGb = W + 20697216;              // 4M
  unsigned short* PH2 = (unsigned short*)(W + 24891520);  // 2M floats
  unsigned short* PL2 = (unsigned short*)(W + 26988672);  // 2M floats

  (void)ws_size;
  float* out = (float*)d_out;

  // merged two-path edge layer
  auto edge2 = [&](const float* xa, int CA, int OA, const float* wa,
                   const float* ga, const float* ba, float* xoutA, int ldoA, int ooffA,
                   const float* xb, int CB, int OB, const float* wb,
                   const float* gb, const float* bb, float* xoutB, int ldoB, int ooffB){
    int KpA = (CA + 15) & ~15, KpB = (CB + 15) & ~15;
    int nkcA = KpA >> 4,       nkcB = KpB >> 4;
    int npairA = 2*OA/64,      npairB = 2*OB/64;
    int nwblkA = ((2*OA/32)*nkcA*64 + 255)/256;
    int nwblkB = ((2*OB/32)*nkcB*64 + 255)/256;
    int nblkA  = nwblkA + 128*nkcA;
    int nblkB  = nwblkB + 128*nkcB;
    int nymfA  = 64*npairA, nymfB = 64*npairB;
    k_pw2<<<nblkA + nblkB, 256, 0, stream>>>(
        xa, PHa, PLa, xxA, wa, PWHa, PWLa, CA, KpA, OA, nwblkA, nblkA,
        xb, PHb, PLb, xxB, wb, PWHb, PWLb, CB, KpB, OB, nwblkB);
    k_dy2<<<(nymfA + 512) + (nymfB + 512), 512, 0, stream>>>(
        PHa, PLa, PWHa, PWLa, xxA, idxA, REGa, KpA, 2*OA, npairA, nymfA,
        PHb, PLb, PWHb, PWLb, xxB, idxB, REGb, KpB, 2*OB, npairB, nymfB);
    int ngridA = 16384/(256/OA);
    int ngridB = 16384/(256/OB);
    k_edge2<<<ngridA + ngridB, 256, 0, stream>>>(
        REGa, idxA, ga, ba, xoutA, OA, ldoA, ooffA, ngridA,
        REGb, idxB, gb, bb, xoutB, OB, ldoB, ooffB);
  };

  // extracts (independent)
  k_ext3<<<(2*8*3*1024+255)/256, 256, 0, stream>>>(f1, f2, Tx0);
  k_extT<<<1024, 256, 0, stream>>>(f1, f2, Ts0);
  // three merged layers (xyz path = A, sem path = B)
  edge2(Tx0, 3,   64, sw1, sg1, sb1, Tx1, 64, 0,
        Ts0, 128, 64, fw1, fg1, fb1, Ts1, 64, 0);
  edge2(Tx1, 64,  64, sw2, sg2, sb2, Tx0, 64, 0,
        Ts1, 64,  64, fw2, fg2, fb2, Ts0, 64, 0);
  edge2(Tx0, 64, 128, sw3, sg3, sb3, X3S3, 256, 0,
        Ts0, 64, 128, fw3, fg3, fb3, X3S3, 256, 128);
  // combine via MFMA: pack X3S3 (K=256) + ew (128x256 plain), then GEMM+epilogue
  {
    int nwblk = ((128/32)*16*64 + 255)/256;          // 16
    k_pw<<<nwblk + 128*16, 256, 0, stream>>>(X3S3, PH2, PL2, xxA, ew, PWHa, PWLa,
        256, 256, 128, nwblk, 128, 0, 0);
    k_emb<<<256, 256, 0, stream>>>(PH2, PL2, PWHa, PWLa, eg, eb, EMB);
  }
  // attention over all 16 batches
  k_meangc<<<16, 1024, 0, stream>>>(EMB, att_w, gcb);
  k_sc<<<4096, 256, 0, stream>>>(EMB, gcb, scb, out + 8);
  k_pool<<<16, 1024, 0, stream>>>(EMB, scb, ep);

  k_tnet<<<8, 256, 0, stream>>>(ep, ep + 1024, tn_w, tn_wb, tn_bias, tsb);
  k_score2<<<1, 128, 0, stream>>>(tsb, fc1_w, fc1_b, sc_w, sc_b, out);
}

// Round 13
// 434.931 us; speedup vs baseline: 1.3196x; 1.0467x over previous
//
#include <hip/hip_runtime.h>
#include <math.h>

#define INV_SQRT1P 0.99999500003749968754f   // 1/sqrt(1+1e-5)

typedef short v8s  __attribute__((ext_vector_type(8)));
typedef float v16f __attribute__((ext_vector_type(16)));

static __device__ __forceinline__ float lrelu(float f){ return f >= 0.0f ? f : 0.2f*f; }

static __device__ __forceinline__ int lanecnt_below(unsigned long long m){
  int c = __builtin_amdgcn_mbcnt_lo((unsigned)m, 0u);
  return __builtin_amdgcn_mbcnt_hi((unsigned)(m >> 32), c);
}

// ---------------- extract xyz (C=3) for BOTH inputs in one launch ----------------
__global__ void k_ext3(const float* __restrict__ f1, const float* __restrict__ f2,
                       float* __restrict__ out){
  int i = blockIdx.x*256 + threadIdx.x;
  int half = 8*3*1024;
  if (i >= 2*half) return;
  const float* f = (i < half) ? f1 : f2;
  int boff = (i < half) ? 0 : 8;
  int ii = (i < half) ? i : i - half;
  int n  = ii & 1023;
  int bc = ii >> 10;
  int c  = bc % 3;
  int b  = bc / 3;
  out[((size_t)(((b+boff)<<10)+n))*3 + c] = f[((size_t)(b*131 + c) << 10) + n];
}

// ---------------- extract sem (C=128) via LDS tile transpose, both inputs ----------
__global__ __launch_bounds__(256) void k_extT(const float* __restrict__ f1,
    const float* __restrict__ f2, float* __restrict__ out){
  __shared__ float T[32][65];
  int bid = blockIdx.x;              // 16 ntile x 4 ctile x 16 (input*8+b)
  int nt = bid & 15;
  int ct = (bid >> 4) & 3;
  int bb = bid >> 6;                 // 0..15
  const float* f = (bb < 8) ? f1 : f2;
  int b = bb & 7;
  int tid = threadIdx.x;
  #pragma unroll
  for (int it=0; it<8; it++){
    int cc = it*4 + (tid >> 6);      // 0..31
    int nn = tid & 63;
    T[cc][nn] = f[((size_t)(b*131 + 3 + ct*32 + cc) << 10) + nt*64 + nn];
  }
  __syncthreads();
  size_t rowb = ((size_t)bb << 10) + nt*64;
  #pragma unroll
  for (int it=0; it<8; it++){
    int nn = it*8 + (tid >> 5);      // 0..63
    int c  = tid & 31;
    out[(rowb + nn)*128 + ct*32 + c] = T[c][nn];
  }
}

// ---------------- pack body (wpack blocks first, then X-pack blocks) ----------------
static __device__ __forceinline__ void pw_body(int bid, int tid,
    const float* __restrict__ X, unsigned short* __restrict__ PH,
    unsigned short* __restrict__ PL, float* __restrict__ xxout,
    const float* __restrict__ Wm, unsigned short* __restrict__ PWH,
    unsigned short* __restrict__ PWL,
    int C, int Kp, int O, int nwblk, int nrowsB, int wsplit, int doxx){
  int nkc = Kp >> 4;
  if (bid < nwblk){
    int gid = bid*256 + tid;
    int nchunk = (nrowsB/32)*nkc;
    if (gid >= nchunk*64) return;
    int lane = gid & 63;
    int chunk = gid >> 6;
    int jb = chunk / nkc, kc = chunk - jb*nkc;
    int j = jb*32 + (lane & 31);
    int k0 = kc*16 + ((lane>>5)<<3);
    unsigned short h[8], lo[8];
    #pragma unroll
    for (int t=0;t<8;t++){
      int k = k0 + t;
      float x = 0.f;
      if (k < C){
        if (wsplit) x = (j < O) ? Wm[(size_t)j*2*C + k] : Wm[(size_t)(j-O)*2*C + C + k];
        else        x = Wm[(size_t)j*C + k];
      }
      unsigned u = __float_as_uint(x);
      unsigned h16 = (u + 0x7fffu + ((u>>16)&1u)) >> 16;
      float hf = __uint_as_float(h16 << 16);
      float lf = x - hf;
      unsigned ul = __float_as_uint(lf);
      unsigned l16 = (ul + 0x7fffu + ((ul>>16)&1u)) >> 16;
      h[t] = (unsigned short)h16; lo[t] = (unsigned short)l16;
    }
    size_t o = (size_t)chunk*512 + lane*8;
    *(v8s*)(PWH + o) = *(v8s*)h;
    *(v8s*)(PWL + o) = *(v8s*)lo;
  } else {
    int gid = (bid - nwblk)*256 + tid;      // grid exact: 512*nkc*64 threads
    int lane = gid & 63;
    int chunk = gid >> 6;
    int rb = chunk / nkc, kc = chunk - rb*nkc;
    int row = rb*32 + (lane & 31);
    int k0 = kc*16 + ((lane>>5)<<3);
    unsigned short h[8], lo[8];
    const float* Xr = X + (size_t)row*C;
    #pragma unroll
    for (int j=0;j<8;j++){
      int k = k0 + j;
      float x = (k < C) ? Xr[k] : 0.f;
      unsigned u = __float_as_uint(x);
      unsigned h16 = (u + 0x7fffu + ((u>>16)&1u)) >> 16;
      float hf = __uint_as_float(h16 << 16);
      float lf = x - hf;
      unsigned ul = __float_as_uint(lf);
      unsigned l16 = (ul + 0x7fffu + ((ul>>16)&1u)) >> 16;
      h[j] = (unsigned short)h16; lo[j] = (unsigned short)l16;
    }
    size_t o = (size_t)chunk*512 + lane*8;
    *(v8s*)(PH + o) = *(v8s*)h;
    *(v8s*)(PL + o) = *(v8s*)lo;
    if (doxx && kc == 0 && (lane & 32) == 0){
      float s = 0.f;
      for (int c=0;c<C;c++) s += Xr[c]*Xr[c];    // ascending order == old k_xx
      xxout[row] = s;
    }
  }
}

// merged pack for two independent paths (layer 1 only) — single call site
__global__ __launch_bounds__(256) void k_pw2(
    const float* __restrict__ XA, unsigned short* __restrict__ PHa,
    unsigned short* __restrict__ PLa, float* __restrict__ xxA,
    const float* __restrict__ WA, unsigned short* __restrict__ PWHa,
    unsigned short* __restrict__ PWLa, int CA, int KpA, int OA, int nwblkA, int nblkA,
    const float* __restrict__ XB, unsigned short* __restrict__ PHb,
    unsigned short* __restrict__ PLb, float* __restrict__ xxB,
    const float* __restrict__ WB, unsigned short* __restrict__ PWHb,
    unsigned short* __restrict__ PWLb, int CB, int KpB, int OB, int nwblkB){
  int bid = blockIdx.x;
  bool isA = bid < nblkA;
  const float* X = isA ? XA : XB;
  unsigned short* PH = isA ? PHa : PHb;
  unsigned short* PL = isA ? PLa : PLb;
  float* xxo = isA ? xxA : xxB;
  const float* Wm = isA ? WA : WB;
  unsigned short* PWH = isA ? PWHa : PWHb;
  unsigned short* PWL = isA ? PWLa : PWLb;
  int C = isA ? CA : CB, Kp = isA ? KpA : KpB, O = isA ? OA : OB;
  int nwblk = isA ? nwblkA : nwblkB;
  int lb = isA ? bid : bid - nblkA;
  pw_body(lb, threadIdx.x, X, PH, PL, xxo, Wm, PWH, PWL, C, Kp, O, nwblk, 2*O, 1, 1);
}

// ---------------- ymf body: Y = X.Wp^T tile per wave ----------------
static __device__ __forceinline__ void ymf_body(int gw, int l,
    const unsigned short* __restrict__ PH, const unsigned short* __restrict__ PL,
    const unsigned short* __restrict__ PWH, const unsigned short* __restrict__ PWL,
    float* __restrict__ Y, int nkc, int N, int npair){
  int mt = gw / npair;
  int pair = gw - mt*npair;
  int jb0 = pair*2, jb1 = pair*2 + 1;
  size_t ao  = ((size_t)mt*nkc)*512 + l*8;
  size_t b0o = ((size_t)jb0*nkc)*512 + l*8;
  size_t b1o = ((size_t)jb1*nkc)*512 + l*8;
  v16f acc0, acc1;
  #pragma unroll
  for (int i=0;i<16;i++){ acc0[i] = 0.f; acc1[i] = 0.f; }
  for (int kc=0; kc<nkc; kc++){
    v8s Ah  = *(const v8s*)(PH + ao);
    v8s Al  = *(const v8s*)(PL + ao);
    v8s B0h = *(const v8s*)(PWH + b0o);
    v8s B0l = *(const v8s*)(PWL + b0o);
    v8s B1h = *(const v8s*)(PWH + b1o);
    v8s B1l = *(const v8s*)(PWL + b1o);
    acc0 = __builtin_amdgcn_mfma_f32_32x32x16_bf16(Ah, B0h, acc0, 0, 0, 0);
    acc1 = __builtin_amdgcn_mfma_f32_32x32x16_bf16(Ah, B1h, acc1, 0, 0, 0);
    acc0 = __builtin_amdgcn_mfma_f32_32x32x16_bf16(Ah, B0l, acc0, 0, 0, 0);
    acc1 = __builtin_amdgcn_mfma_f32_32x32x16_bf16(Ah, B1l, acc1, 0, 0, 0);
    acc0 = __builtin_amdgcn_mfma_f32_32x32x16_bf16(Al, B0h, acc0, 0, 0, 0);
    acc1 = __builtin_amdgcn_mfma_f32_32x32x16_bf16(Al, B1h, acc1, 0, 0, 0);
    ao += 512; b0o += 512; b1o += 512;
  }
  int rbase = mt*32;
  int c0 = pair*64 + (l & 31), c1 = c0 + 32;
  #pragma unroll
  for (int r=0;r<16;r++){
    int rl_ = (r&3) + ((r>>2)<<3) + ((l>>5)<<2);
    float* dst = Y + (size_t)(rbase + rl_)*N;
    dst[c0] = acc0[r];
    dst[c1] = acc1[r];
  }
}

// ---------------- dtk body: distances + exact top-20 for rowblock rb ----------------
static __device__ __forceinline__ void dtk_body(float (&Sl)[16][1024], int t, int wave, int l,
    const unsigned short* __restrict__ PH, const unsigned short* __restrict__ PL,
    const float* __restrict__ xx, int* __restrict__ idx, int nkc){
  int rb = ((t & 7) << 6) | (t >> 3);   // XCD swizzle over 512 dtk blocks
  int batch = rb >> 5;
  const float* xxb = xx + (batch<<10);
  int rbase_local = (rb & 31)*32;

  v16f acc[4];
  #pragma unroll
  for (int i=0;i<4;i++){
    #pragma unroll
    for (int j=0;j<16;j++) acc[i][j] = 0.f;
  }
  #pragma unroll
  for (int pp=0; pp<2; pp++){
    int pair = wave*2 + pp;
    size_t a   = ((size_t)rb*nkc)*512 + l*8;
    size_t b0o = ((size_t)(batch*32 + 2*pair)*nkc)*512 + l*8;
    size_t b1o = b0o + (size_t)nkc*512;
    for (int kc=0; kc<nkc; kc++){
      v8s Ah  = *(const v8s*)(PH + a);
      v8s Al  = *(const v8s*)(PL + a);
      v8s B0h = *(const v8s*)(PH + b0o);
      v8s B0l = *(const v8s*)(PL + b0o);
      v8s B1h = *(const v8s*)(PH + b1o);
      v8s B1l = *(const v8s*)(PL + b1o);
      acc[2*pp]   = __builtin_amdgcn_mfma_f32_32x32x16_bf16(Ah, B0h, acc[2*pp],   0, 0, 0);
      acc[2*pp+1] = __builtin_amdgcn_mfma_f32_32x32x16_bf16(Ah, B1h, acc[2*pp+1], 0, 0, 0);
      acc[2*pp]   = __builtin_amdgcn_mfma_f32_32x32x16_bf16(Ah, B0l, acc[2*pp],   0, 0, 0);
      acc[2*pp+1] = __builtin_amdgcn_mfma_f32_32x32x16_bf16(Ah, B1l, acc[2*pp+1], 0, 0, 0);
      acc[2*pp]   = __builtin_amdgcn_mfma_f32_32x32x16_bf16(Al, B0h, acc[2*pp],   0, 0, 0);
      acc[2*pp+1] = __builtin_amdgcn_mfma_f32_32x32x16_bf16(Al, B1h, acc[2*pp+1], 0, 0, 0);
      a += 512; b0o += 512; b1o += 512;
    }
  }

  #pragma unroll
  for (int h=0; h<2; h++){
    #pragma unroll
    for (int pp=0; pp<2; pp++){
      int pair = wave*2 + pp;
      int c0 = pair*64 + (l & 31), c1 = c0 + 32;
      float xc0 = xxb[c0], xc1 = xxb[c1];
      #pragma unroll
      for (int r = 0; r < 8; r++){
        int rr = h*8 + r;
        int rl = (rr&3) + (((rr>>2)&1)<<3) + ((l>>5)<<2);  // 0..15
        float xr = xxb[rbase_local + h*16 + rl];
        Sl[rl][c0] = 2.f*acc[2*pp][rr]   - xr - xc0;
        Sl[rl][c1] = 2.f*acc[2*pp+1][rr] - xr - xc1;
      }
    }
    __syncthreads();
    {
      int hi = l >> 5;
      int li = l & 31;
      int rloc = wave*2 + hi;
      int grow = rb*32 + h*16 + rloc;
      int out_base = grow*20;
      unsigned long long hm = hi ? 0xFFFFFFFF00000000ull : 0x00000000FFFFFFFFull;

      unsigned kv[32];
      #pragma unroll
      for (int j=0;j<32;j++){
        unsigned u = __float_as_uint(Sl[rloc][li + 32*j]);
        kv[j] = (u & 0x80000000u) ? ~u : (u | 0x80000000u);
      }

      unsigned lmax = kv[0];
      #pragma unroll
      for (int j=1;j<32;j++) lmax = lmax > kv[j] ? lmax : kv[j];

      unsigned tau = 0u;
      #pragma unroll
      for (int bit=31; bit>=0; --bit){
        unsigned cand = tau | (1u << bit);
        unsigned long long M = __ballot(lmax >= cand);
        int c = hi ? __popc((unsigned)(M >> 32)) : __popc((unsigned)M);
        tau = (c >= 20) ? cand : tau;
      }

      unsigned long long* sl = (unsigned long long*)&Sl[rloc][0];
      sl[li] = 0ull; sl[li+32] = 0ull;
      int b2 = 0;
      #pragma unroll
      for (int j=0;j<32;j++){
        bool p = kv[j] >= tau;
        unsigned long long M = __ballot(p) & hm;
        if (p){
          int s = b2 + lanecnt_below(M);
          if (s < 64) sl[s] = ((unsigned long long)kv[j] << 32) | (unsigned)(li + 32*j);
        }
        b2 += __popcll(M);
      }

      if (b2 <= 64){
        unsigned long long pk0 = sl[li], pk1 = sl[li+32];
        unsigned vcur = 0u;
        #pragma unroll
        for (int bit=31; bit>=0; --bit){
          unsigned long long cc = (unsigned long long)(vcur | (1u << bit)) << 32;
          unsigned long long B0 = __ballot(pk0 >= cc);
          unsigned long long B1 = __ballot(pk1 >= cc);
          int clo = __popc((unsigned)B0) + __popc((unsigned)B1);
          int chi = __popc((unsigned)(B0>>32)) + __popc((unsigned)(B1>>32));
          int c = hi ? chi : clo;
          vcur = (c >= 20) ? (vcur | (1u << bit)) : vcur;
        }
        unsigned k0 = (unsigned)(pk0 >> 32), k1 = (unsigned)(pk1 >> 32);
        unsigned long long G0 = __ballot(k0 > vcur) & hm;
        unsigned long long G1 = __ballot(k1 > vcur) & hm;
        int ng0 = __popcll(G0);
        int c1  = ng0 + __popcll(G1);
        if (k0 > vcur) idx[out_base + lanecnt_below(G0)] = (int)(pk0 & 0xffffffffu);
        if (k1 > vcur) idx[out_base + ng0 + lanecnt_below(G1)] = (int)(pk1 & 0xffffffffu);
        unsigned long long E0 = __ballot(k0 == vcur) & hm;
        unsigned long long E1 = __ballot(k1 == vcur) & hm;
        int ne0 = __popcll(E0);
        if (k0 == vcur){ int s = c1 + lanecnt_below(E0); if (s < 20) idx[out_base + s] = (int)(pk0 & 0xffffffffu); }
        if (k1 == vcur){ int s = c1 + ne0 + lanecnt_below(E1); if (s < 20) idx[out_base + s] = (int)(pk1 & 0xffffffffu); }
      } else {
        unsigned cur = 0u;
        #pragma unroll 1
        for (int bit=31; bit>=0; --bit){
          unsigned cand = cur | (1u << bit);
          int lc = 0;
          #pragma unroll
          for (int j=0;j<32;j++) lc += (kv[j] >= cand) ? 1 : 0;
          #pragma unroll
          for (int off=1; off<32; off<<=1) lc += __shfl_xor(lc, off, 64);
          cur = (lc >= 20) ? cand : cur;
        }
        int bse = 0;
        #pragma unroll 1
        for (int j=0;j<32;j++){
          unsigned long long Mg = __ballot(kv[j] > cur) & hm;
          if (kv[j] > cur){ int s = bse + lanecnt_below(Mg); idx[out_base + s] = li + 32*j; }
          bse += __popcll(Mg);
        }
        #pragma unroll 1
        for (int j=0;j<32;j++){
          unsigned long long Me = __ballot(kv[j] == cur) & hm;
          if (kv[j] == cur){ int s = bse + lanecnt_below(Me); if (s < 20) idx[out_base + s] = li + 32*j; }
          bse += __popcll(Me);
          if (bse >= 20) break;
        }
      }
    }
    __syncthreads();
  }
}

// merged Y-GEMM + distance/top-20 for TWO independent paths (single call sites)
__global__ __launch_bounds__(512) void k_dy2(
    const unsigned short* __restrict__ PHa, const unsigned short* __restrict__ PLa,
    const unsigned short* __restrict__ PWHa, const unsigned short* __restrict__ PWLa,
    const float* __restrict__ xxA, int* __restrict__ idxA, float* __restrict__ Ya,
    int KpA, int NA, int npairA, int nymfA,
    const unsigned short* __restrict__ PHb, const unsigned short* __restrict__ PLb,
    const unsigned short* __restrict__ PWHb, const unsigned short* __restrict__ PWLb,
    const float* __restrict__ xxB, int* __restrict__ idxB, float* __restrict__ Yb,
    int KpB, int NB, int npairB, int nymfB){
  __shared__ float Sl[16][1024];          // 64 KB
  int wave = threadIdx.x >> 6;
  int l = threadIdx.x & 63;
  int bid = (int)blockIdx.x;
  int nblkA = nymfA + 512;
  bool isA = bid < nblkA;
  const unsigned short* PH  = isA ? PHa  : PHb;
  const unsigned short* PL  = isA ? PLa  : PLb;
  const unsigned short* PWH = isA ? PWHa : PWHb;
  const unsigned short* PWL = isA ? PWLa : PWLb;
  const float* xx = isA ? xxA : xxB;
  int* idx  = isA ? idxA : idxB;
  float* Y  = isA ? Ya : Yb;
  int Kp    = isA ? KpA : KpB;
  int N     = isA ? NA  : NB;
  int npair = isA ? npairA : npairB;
  int nymf  = isA ? nymfA  : nymfB;
  int lb    = isA ? bid : bid - nblkA;
  if (lb < nymf)
    ymf_body(lb*8 + wave, l, PH, PL, PWH, PWL, Y, Kp >> 4, N, npair);
  else
    dtk_body(Sl, lb - nymf, wave, l, PH, PL, xx, idx, Kp >> 4);
}

// ---------------- fused edge + next-layer pack (+xx) body ----------------
// Edge math identical to old k_edge2. Instead of writing T, packs the bf16 hi/lo
// fragments directly (same values/addresses as pw_body would produce) and computes
// xx[row] via per-row wave tree-reduce (order differs from serial; <=1ulp on dist).
static __device__ __forceinline__ void ep_body(int bid, int tid,
    float (&Bsh)[512], int (&js)[4][20],
    const float* __restrict__ Y, const int* __restrict__ idx,
    const float* __restrict__ g, const float* __restrict__ bias,
    unsigned short* __restrict__ PH, unsigned short* __restrict__ PL,
    float* __restrict__ xxout, int O, int kcoff, int nkcT, int doxx){
  int rpb = 256/O;
  int rloc = tid/O;
  int o = tid - rloc*O;
  int row0 = bid*rpb;
  int row = row0 + rloc;
  int b = row >> 10;
  if (tid < rpb*20) js[tid/20][tid%20] = idx[row0*20 + tid];
  __syncthreads();
  int O2 = O*2;
  float y1c = Y[(size_t)row*O2 + o];
  float d   = Y[(size_t)row*O2 + O + o] - y1c;
  float sc  = g[o] * INV_SQRT1P;
  float bb  = bias[o];
  const float* Yb = Y + ((size_t)(b<<10))*O2;
  float best = -1e38f;
  #pragma unroll
  for (int k=0;k<20;k++){
    float f = sc * (Yb[(size_t)js[rloc][k]*O2 + o] + d) + bb;
    best = fmaxf(best, lrelu(f));
  }
  Bsh[rloc*O + o] = best;
  __syncthreads();
  int wave = tid >> 6, l = tid & 63;
  if (doxx && wave < rpb){
    float s = 0.f;
    for (int t=l; t<O; t+=64){ float v = Bsh[wave*O + t]; s += v*v; }
    #pragma unroll
    for (int off=32; off>0; off>>=1) s += __shfl_xor(s, off, 64);
    if (l == 0) xxout[row0 + wave] = s;
  }
  // pack: 32 tasks = rpb rows x (O/16) local chunks x 2 half-lanes
  if (tid < 32){
    int perrow = (O >> 4)*2;
    int r2 = tid / perrow, pos = tid - r2*perrow;
    int kcl = pos >> 1, half = pos & 1;
    int row2 = row0 + r2, rb32 = row2 >> 5, lr = row2 & 31;
    int k0 = kcl*16 + half*8;
    unsigned short h[8], lo8[8];
    #pragma unroll
    for (int j=0;j<8;j++){
      float x = Bsh[r2*O + k0 + j];
      unsigned u = __float_as_uint(x);
      unsigned h16 = (u + 0x7fffu + ((u>>16)&1u)) >> 16;
      float hf = __uint_as_float(h16 << 16);
      float lf = x - hf;
      unsigned ul = __float_as_uint(lf);
      unsigned l16 = (ul + 0x7fffu + ((ul>>16)&1u)) >> 16;
      h[j] = (unsigned short)h16; lo8[j] = (unsigned short)l16;
    }
    size_t off = ((size_t)(rb32*nkcT + kcoff + kcl))*512 + (half*32 + lr)*8;
    *(v8s*)(PH + off) = *(v8s*)h;
    *(v8s*)(PL + off) = *(v8s*)lo8;
  }
}

// fused kernel: [wpackA | wpackB | edge+pack A | edge+pack B]
__global__ __launch_bounds__(256) void k_ep2(
    const float* __restrict__ WmA, unsigned short* __restrict__ PWHa2,
    unsigned short* __restrict__ PWLa2, int CwA, int KpwA, int OwA, int wsA, int nrA, int nwA,
    const float* __restrict__ WmB, unsigned short* __restrict__ PWHb2,
    unsigned short* __restrict__ PWLb2, int CwB, int KpwB, int OwB, int wsB, int nrB, int nwB,
    const float* __restrict__ Ya, const int* __restrict__ idxA,
    const float* __restrict__ gA, const float* __restrict__ bA,
    unsigned short* __restrict__ PHa2, unsigned short* __restrict__ PLa2,
    float* __restrict__ xxA2, int OA, int kcoffA, int nkcA, int doxxA, int ngeA,
    const float* __restrict__ Yb, const int* __restrict__ idxB,
    const float* __restrict__ gB, const float* __restrict__ bB,
    unsigned short* __restrict__ PHb2, unsigned short* __restrict__ PLb2,
    float* __restrict__ xxB2, int OB, int kcoffB, int nkcB, int doxxB){
  __shared__ float Bsh[512];
  __shared__ int js[4][20];
  int bid = (int)blockIdx.x, tid = threadIdx.x;
  int nw = nwA + nwB;
  if (bid < nw){
    bool isA = bid < nwA;
    const float* Wm = isA ? WmA : WmB;
    unsigned short* PWH = isA ? PWHa2 : PWHb2;
    unsigned short* PWL = isA ? PWLa2 : PWLb2;
    int C = isA ? CwA : CwB, Kp = isA ? KpwA : KpwB, O = isA ? OwA : OwB;
    int ws = isA ? wsA : wsB, nr = isA ? nrA : nrB;
    int lb = isA ? bid : bid - nwA;
    pw_body(lb, tid, (const float*)0, (unsigned short*)0, (unsigned short*)0,
            (float*)0, Wm, PWH, PWL, C, Kp, O, 1<<30, nr, ws, 0);
  } else {
    int eb = bid - nw;
    bool isA = eb < ngeA;
    const float* Y = isA ? Ya : Yb;
    const int* idx = isA ? idxA : idxB;
    const float* g = isA ? gA : gB;
    const float* bi = isA ? bA : bB;
    unsigned short* PH = isA ? PHa2 : PHb2;
    unsigned short* PL = isA ? PLa2 : PLb2;
    float* xxo = isA ? xxA2 : xxB2;
    int O = isA ? OA : OB, kcoff = isA ? kcoffA : kcoffB;
    int nkcT = isA ? nkcA : nkcB, doxx = isA ? doxxA : doxxB;
    int lb = isA ? eb : eb - ngeA;
    ep_body(lb, tid, Bsh, js, Y, idx, g, bi, PH, PL, xxo, O, kcoff, nkcT, doxx);
  }
}

// ---------------- EMB combine via MFMA: EMB = lrelu(eg*(X3S3.ew^T)*inv + eb) --------
__global__ __launch_bounds__(256) void k_emb(const unsigned short* __restrict__ PH,
    const unsigned short* __restrict__ PL, const unsigned short* __restrict__ PWH,
    const unsigned short* __restrict__ PWL, const float* __restrict__ eg,
    const float* __restrict__ eb, float* __restrict__ EMB){
  int w = threadIdx.x >> 6;
  int l = threadIdx.x & 63;
  int gw = blockIdx.x*4 + w;
  int mt = gw >> 1, pair = gw & 1;
  const int nkc = 16;
  size_t ao  = ((size_t)mt*nkc)*512 + l*8;
  size_t b0o = ((size_t)(pair*2)*nkc)*512 + l*8;
  size_t b1o = b0o + (size_t)nkc*512;
  v16f acc0, acc1;
  #pragma unroll
  for (int i=0;i<16;i++){ acc0[i] = 0.f; acc1[i] = 0.f; }
  for (int kc=0; kc<nkc; kc++){
    v8s Ah  = *(const v8s*)(PH + ao);
    v8s Al  = *(const v8s*)(PL + ao);
    v8s B0h = *(const v8s*)(PWH + b0o);
    v8s B0l = *(const v8s*)(PWL + b0o);
    v8s B1h = *(const v8s*)(PWH + b1o);
    v8s B1l = *(const v8s*)(PWL + b1o);
    acc0 = __builtin_amdgcn_mfma_f32_32x32x16_bf16(Ah, B0h, acc0, 0, 0, 0);
    acc1 = __builtin_amdgcn_mfma_f32_32x32x16_bf16(Ah, B1h, acc1, 0, 0, 0);
    acc0 = __builtin_amdgcn_mfma_f32_32x32x16_bf16(Ah, B0l, acc0, 0, 0, 0);
    acc1 = __builtin_amdgcn_mfma_f32_32x32x16_bf16(Ah, B1l, acc1, 0, 0, 0);
    acc0 = __builtin_amdgcn_mfma_f32_32x32x16_bf16(Al, B0h, acc0, 0, 0, 0);
    acc1 = __builtin_amdgcn_mfma_f32_32x32x16_bf16(Al, B1h, acc1, 0, 0, 0);
    ao += 512; b0o += 512; b1o += 512;
  }
  int rbase = mt*32;
  int c0 = pair*64 + (l & 31), c1 = c0 + 32;
  float g0 = eg[c0]*INV_SQRT1P, g1 = eg[c1]*INV_SQRT1P;
  float bb0 = eb[c0], bb1 = eb[c1];
  #pragma unroll
  for (int r=0;r<16;r++){
    int rl_ = (r&3) + ((r>>2)<<3) + ((l>>5)<<2);
    float* dst = EMB + (size_t)(rbase + rl_)*128;
    dst[c0] = lrelu(g0*acc0[r] + bb0);
    dst[c1] = lrelu(g1*acc1[r] + bb1);
  }
}

// ---------------- attention (16 batches): fused mean + gc ----------------
__global__ __launch_bounds__(1024) void k_meangc(const float* __restrict__ emb,
     const float* __restrict__ att_w, float* __restrict__ gc){
  int b = blockIdx.x; int f = threadIdx.x & 127; int ny = threadIdx.x >> 7;
  const float* e = emb + ((size_t)(b<<10) + ny*128)*128 + f;
  float s = 0.f;
  for (int n=0;n<128;n++) s += e[n*128];
  __shared__ float red[8][128];
  __shared__ float mr[128];
  red[ny][f] = s;
  __syncthreads();
  if (ny == 0){
    float t = 0.f;
    #pragma unroll
    for (int i=0;i<8;i++) t += red[i][f];
    mr[f] = t * (1.0f/1024.0f);
  }
  __syncthreads();
  if (threadIdx.x < 128){
    int g = threadIdx.x;
    float s2 = 0.f;
    for (int ff=0; ff<128; ff++) s2 += mr[ff]*att_w[ff*128+g];
    gc[b*128+g] = tanhf(s2);
  }
}

// ---------------- sc: 4 rows per block (4 waves) ----------------
__global__ __launch_bounds__(256) void k_sc(const float* __restrict__ emb, const float* __restrict__ gc,
     float* __restrict__ sc, float* __restrict__ attout){
  int wave = threadIdx.x >> 6;
  int l = threadIdx.x & 63;
  int row = blockIdx.x*4 + wave;
  int b = row >> 10;
  const float* e  = emb + (size_t)row*128;
  const float* gb = gc + b*128;
  float p = e[l]*gb[l] + e[l+64]*gb[l+64];
  #pragma unroll
  for (int off=32; off>0; off>>=1) p += __shfl_xor(p, off, 64);
  if (l == 0){
    float s = 1.0f/(1.0f + expf(-p));
    sc[row] = s;
    attout[row] = s;
  }
}

__global__ __launch_bounds__(1024) void k_pool(const float* __restrict__ emb, const float* __restrict__ sc,
     float* __restrict__ ep){
  int b = blockIdx.x; int f = threadIdx.x & 127; int ny = threadIdx.x >> 7;
  const float* e  = emb + ((size_t)(b<<10) + ny*128)*128 + f;
  const float* sb = sc + (b<<10) + ny*128;
  float s = 0.f;
  for (int n=0;n<128;n++) s += e[n*128]*sb[n];
  __shared__ float red[8][128];
  red[ny][f] = s;
  __syncthreads();
  if (ny == 0){
    float t = 0.f;
    #pragma unroll
    for (int i=0;i<8;i++) t += red[i][f];
    ep[b*128+f] = t;
  }
}

// ---------------- tensor network scoring ----------------
__global__ __launch_bounds__(256) void k_tnet(const float* __restrict__ e1, const float* __restrict__ e2,
    const float* __restrict__ tn_w, const float* __restrict__ tn_wb, const float* __restrict__ tn_bias,
    float* __restrict__ tsout){
  int b = blockIdx.x; int t = threadIdx.x; int tt = t & 15; int fs = t >> 4;
  __shared__ float E1[128], E2[128], red[16][17];
  if (t < 128){ E1[t] = e1[b*128+t]; E2[t] = e2[b*128+t]; }
  __syncthreads();
  float acc = 0.f;
  for (int f = fs*8; f < fs*8+8; f++){
    const float* tw = tn_w + f*128*16 + tt;
    float partial = 0.f;
    for (int g=0; g<128; g++) partial += E2[g]*tw[g*16];
    acc += E1[f]*partial;
  }
  red[fs][tt] = acc;
  __syncthreads();
  if (t < 16){
    float s = 0.f;
    #pragma unroll
    for (int i=0;i<16;i++) s += red[i][t];
    float acc2 = 0.f;
    for (int c=0;c<128;c++) acc2 += tn_wb[t*256+c]*E1[c] + tn_wb[t*256+128+c]*E2[c];
    float v = s + acc2 + tn_bias[t];
    tsout[b*16+t] = v > 0.f ? v : 0.f;
  }
}

__global__ __launch_bounds__(128) void k_score2(const float* __restrict__ ts,
   const float* __restrict__ fc1_w, const float* __restrict__ fc1_b,
   const float* __restrict__ sc_w, const float* __restrict__ sc_b, float* __restrict__ out){
  int t = threadIdx.x; int b = t >> 4, i = t & 15;
  __shared__ float h2[8][17];
  float a = 0.f;
  #pragma unroll
  for (int k=0;k<16;k++) a += ts[b*16+k]*fc1_w[i*16+k];
  a += fc1_b[i];
  h2[b][i] = a > 0.f ? a : 0.f;
  __syncthreads();
  if (t < 8){
    float s = 0.f;
    #pragma unroll
    for (int k=0;k<16;k++) s += h2[t][k]*sc_w[k];
    s += sc_b[0];
    out[t] = 1.0f/(1.0f + expf(-s));
  }
}

extern "C" void kernel_launch(void* const* d_in, const int* in_sizes, int n_in,
                              void* d_out, int out_size, void* d_ws, size_t ws_size,
                              hipStream_t stream){
  const float* f1  = (const float*)d_in[0];
  const float* f2  = (const float*)d_in[1];
  const float* sw1 = (const float*)d_in[2];  const float* sg1 = (const float*)d_in[3];  const float* sb1 = (const float*)d_in[4];
  const float* fw1 = (const float*)d_in[5];  const float* fg1 = (const float*)d_in[6];  const float* fb1 = (const float*)d_in[7];
  const float* sw2 = (const float*)d_in[8];  const float* sg2 = (const float*)d_in[9];  const float* sb2 = (const float*)d_in[10];
  const float* fw2 = (const float*)d_in[11]; const float* fg2 = (const float*)d_in[12]; const float* fb2 = (const float*)d_in[13];
  const float* sw3 = (const float*)d_in[14]; const float* sg3 = (const float*)d_in[15]; const float* sb3 = (const float*)d_in[16];
  const float* fw3 = (const float*)d_in[17]; const float* fg3 = (const float*)d_in[18]; const float* fb3 = (const float*)d_in[19];
  const float* ew  = (const float*)d_in[20]; const float* eg  = (const float*)d_in[21]; const float* eb  = (const float*)d_in[22];
  const float* att_w   = (const float*)d_in[23];
  const float* tn_w    = (const float*)d_in[24];
  const float* tn_wb   = (const float*)d_in[25];
  const float* tn_bias = (const float*)d_in[26];
  const float* fc1_w   = (const float*)d_in[27];
  const float* fc1_b   = (const float*)d_in[28];
  const float* sc_w    = (const float*)d_in[29];
  const float* sc_b    = (const float*)d_in[30];

  float* W    = (float*)d_ws;
  float* Tx0  = W;                         // 1M (16384 x <=64)
  float* Ts0  = W + 2097152;               // 2M (16384 x 128)
  float* EMB  = W + 9437184;               // 2M
  float* xxA  = W + 11534336;              // 16384
  float* xxB  = W + 11550720;              // 16384
  float* gcb  = W + 11567104;              // 2048
  float* scb  = W + 11569152;              // 16384
  float* ep   = W + 11585536;              // 2048
  float* tsb  = W + 11587584;              // 128
  int*   idxA = (int*)(W + 11587712);      // 327680 ints
  int*   idxB = (int*)(W + 11915392);      // 327680 ints
  unsigned short* PHa  = (unsigned short*)(W + 12243072); // 1M floats
  unsigned short* PLa  = (unsigned short*)(W + 13291648);
  unsigned short* PHb  = (unsigned short*)(W + 14340224);
  unsigned short* PLb  = (unsigned short*)(W + 15388800);
  unsigned short* PWHa = (unsigned short*)(W + 16437376); // 16K floats
  unsigned short* PWLa = (unsigned short*)(W + 16453760);
  unsigned short* PWHb = (unsigned short*)(W + 16470144);
  unsigned short* PWLb = (unsigned short*)(W + 16486528);
  float* REGa = W + 16502912;              // 4M
  float* REGb = W + 20697216;              // 4M
  unsigned short* PH2 = (unsigned short*)(W + 24891520);  // 2M floats
  unsigned short* PL2 = (unsigned short*)(W + 26988672);  // 2M floats

  (void)ws_size;
  float* out = (float*)d_out;

  // extracts (independent)
  k_ext3<<<(2*8*3*1024+255)/256, 256, 0, stream>>>(f1, f2, Tx0);
  k_extT<<<1024, 256, 0, stream>>>(f1, f2, Ts0);

  // ---- layer 1: pack from extracts (A: xyz C=3, B: sem C=128) + W1 ----
  {
    int nwblkA = ((2*64/32)*1*64 + 255)/256;   // 1
    int nwblkB = ((2*64/32)*8*64 + 255)/256;   // 8
    int nblkA  = nwblkA + 128*1;               // 129
    int nblkB  = nwblkB + 128*8;               // 1032
    k_pw2<<<nblkA + nblkB, 256, 0, stream>>>(
        Tx0, PHa, PLa, xxA, sw1, PWHa, PWLa, 3, 16, 64, nwblkA, nblkA,
        Ts0, PHb, PLb, xxB, fw1, PWHb, PWLb, 128, 128, 64, nwblkB);
    k_dy2<<<(128+512)+(128+512), 512, 0, stream>>>(
        PHa, PLa, PWHa, PWLa, xxA, idxA, REGa, 16, 128, 2, 128,
        PHb, PLb, PWHb, PWLb, xxB, idxB, REGb, 128, 128, 2, 128);
  }
  // ---- fused: edge L1 + pack L2 (C=64) + wpack W2 ----
  k_ep2<<<4+4+4096+4096, 256, 0, stream>>>(
      sw2, PWHa, PWLa, 64, 64, 64, 1, 128, 4,
      fw2, PWHb, PWLb, 64, 64, 64, 1, 128, 4,
      REGa, idxA, sg1, sb1, PHa, PLa, xxA, 64, 0, 4, 1, 4096,
      REGb, idxB, fg1, fb1, PHb, PLb, xxB, 64, 0, 4, 1);
  k_dy2<<<(128+512)+(128+512), 512, 0, stream>>>(
      PHa, PLa, PWHa, PWLa, xxA, idxA, REGa, 64, 128, 2, 128,
      PHb, PLb, PWHb, PWLb, xxB, idxB, REGb, 64, 128, 2, 128);
  // ---- fused: edge L2 + pack L3 (C=64) + wpack W3 ----
  k_ep2<<<8+8+4096+4096, 256, 0, stream>>>(
      sw3, PWHa, PWLa, 64, 64, 128, 1, 256, 8,
      fw3, PWHb, PWLb, 64, 64, 128, 1, 256, 8,
      REGa, idxA, sg2, sb2, PHa, PLa, xxA, 64, 0, 4, 1, 4096,
      REGb, idxB, fg2, fb2, PHb, PLb, xxB, 64, 0, 4, 1);
  k_dy2<<<(256+512)+(256+512), 512, 0, stream>>>(
      PHa, PLa, PWHa, PWLa, xxA, idxA, REGa, 64, 256, 4, 256,
      PHb, PLb, PWHb, PWLb, xxB, idxB, REGb, 64, 256, 4, 256);
  // ---- fused: edge L3 + pack emb A (K=256, shared PH2: A->kc 0..7, B->kc 8..15) + wpack ew ----
  k_ep2<<<16+0+8192+8192, 256, 0, stream>>>(
      ew, PWHa, PWLa, 256, 256, 128, 0, 128, 16,
      ew, PWHb, PWLb, 256, 256, 128, 0, 128, 0,
      REGa, idxA, sg3, sb3, PH2, PL2, xxA, 128, 0, 16, 0, 8192,
      REGb, idxB, fg3, fb3, PH2, PL2, xxB, 128, 8, 16, 0);
  k_emb<<<256, 256, 0, stream>>>(PH2, PL2, PWHa, PWLa, eg, eb, EMB);
  // attention over all 16 batches
  k_meangc<<<16, 1024, 0, stream>>>(EMB, att_w, gcb);
  k_sc<<<4096, 256, 0, stream>>>(EMB, gcb, scb, out + 8);
  k_pool<<<16, 1024, 0, stream>>>(EMB, scb, ep);

  k_tnet<<<8, 256, 0, stream>>>(ep, ep + 1024, tn_w, tn_wb, tn_bias, tsb);
  k_score2<<<1, 128, 0, stream>>>(tsb, fc1_w, fc1_b, sc_w, sc_b, out);
}